// Round 7
// baseline (299.156 us; speedup 1.0000x reference)
//
#include <hip/hip_runtime.h>

// ---------------------------------------------------------------------------
// B=16, L=1024, D=256, H=4 (DH=64), DFF=2048, C=3. Output: 17 elems.
// Dtype-adaptive (f32 or bf16 inputs; mode from DETP partial sums). Wq/bq
// pre-scaled by 0.125*log2e so attention softmax is bare exp2.
// r24: k_ffn fuses FFN1+FFN2 — Hb (64MB write + 64MB read HBM) never
// materialized. Per block: 64 rows; Y1 tile register-cached (reused over 32
// DFF-chunks); per chunk stage W1/W2 (double-buffered, r19 overlap), GEMM1
// via r18 swapped-MFMA (lane gets 4 contiguous dff -> u16x4 H writes into
// padded Hs[64][68]), bf16-quantize H (= old Hb), GEMM2 accumulates FFO in
// regs. MFMA chain order identical to old pair -> bit-identical FFO.
// 11 launches. r23: prep+embed merge, predhead fusion. r22: k_wo_ln.
// r19: attention dbuf K/V + register prefetch. r18: in-register P.
// ---------------------------------------------------------------------------

typedef unsigned short u16;
typedef u16    u16x4  __attribute__((ext_vector_type(4)));
typedef u16    u16x8  __attribute__((ext_vector_type(8)));
typedef __bf16 bf16x8 __attribute__((ext_vector_type(8)));
typedef float  f32x4  __attribute__((ext_vector_type(4)));

__device__ __forceinline__ float bf2f(u16 u) {
    union { unsigned int i; float f; } v; v.i = ((unsigned int)u) << 16; return v.f;
}
__device__ __forceinline__ u16 f2bf(float f) {
    union { float f; unsigned int i; } v; v.f = f;
    unsigned int r = (v.i + 0x7FFFu + ((v.i >> 16) & 1u)) >> 16;
    return (u16)r;
}
__device__ __forceinline__ u16 f2bf_fast(float f) {
    union { __bf16 h; u16 u; } v; v.h = (__bf16)f; return v.u;
}
__device__ __forceinline__ void gll16(const u16* g, u16* l) {
    __builtin_amdgcn_global_load_lds((__attribute__((address_space(1))) void*)(u16*)g,
                                     (__attribute__((address_space(3))) void*)l, 16, 0, 0);
}
__device__ __forceinline__ int get_mode(const int* __restrict__ detp) {
    int s = 0;
#pragma unroll 8
    for (int i = 0; i < 64; ++i) s += detp[i];
    return s > 16;
}

// ---------------- dtype detection: plain per-block partials ----------------
__global__ __launch_bounds__(256) void k_detect(const u16* __restrict__ w1raw,
                                                int* __restrict__ detp) {
    int i = blockIdx.x * 256 + threadIdx.x;
    int bad = 0;
    for (int k = i; k < 65536; k += 64 * 256) {
        unsigned v = w1raw[k] & 0x7FFFu;
        if (v >= 0x7F80u) bad++;
    }
    for (int off = 32; off >= 1; off >>= 1) bad += __shfl_xor(bad, off);
    __shared__ int bs[4];
    if ((threadIdx.x & 63) == 0) bs[threadIdx.x >> 6] = bad;
    __syncthreads();
    if (threadIdx.x == 0) detp[blockIdx.x] = bs[0] + bs[1] + bs[2] + bs[3];
}
__global__ void k_sentinel_f32(float* __restrict__ out, int code) {
    int t = threadIdx.x;
    if (t < 17) out[t] = (float)code;
}

// ------- prep: transposes + small ingest + embedding, one launch -----------
struct PrepTab {
    const void* src[7];
    u16*        dst[7];
    int         K[7], N[7];
    float       scale[7];
    int         tstart[8];     // transpose tile ranges; ingest = [tstart[7], +17)
    const void* isrc[17];
    unsigned    idstoff[17];
    int         in[17];
    float       iscale[17];
    u16*        ing;
    int         estart;        // embed blocks start here
    const int*  si;
    const int*  ci;
    const void* se;
    const void* ce;
    u16*        X;
};
__global__ __launch_bounds__(256) void k_prep(PrepTab tt, const int* __restrict__ detp) {
    int m = get_mode(detp);
    int bx = blockIdx.x;
    if (bx >= tt.estart) {                    // ---- embedding ----
        int t = (bx - tt.estart) * 256 + threadIdx.x;
        int row = t >> 5, seg = (t & 31) * 8;
        int s = tt.si[row], c = tt.ci[row];
        u16x8 o;
        if (m) {
            const float* sp = (const float*)tt.se + s * 256 + seg;
            const float* cp = (const float*)tt.ce + c * 256 + seg;
#pragma unroll
            for (int e = 0; e < 8; ++e) o[e] = f2bf(sp[e] + cp[e]);
        } else {
            u16x8 a = *(const u16x8*)((const u16*)tt.se + s * 256 + seg);
            u16x8 b = *(const u16x8*)((const u16*)tt.ce + c * 256 + seg);
#pragma unroll
            for (int e = 0; e < 8; ++e) o[e] = f2bf(bf2f(a[e]) + bf2f(b[e]));
        }
        *(u16x8*)&tt.X[(size_t)row * 256 + seg] = o;
        return;
    }
    if (bx >= tt.tstart[7]) {                 // ---- small-tensor ingest ----
        int t = bx - tt.tstart[7];
        int n = tt.in[t];
        float sc = tt.iscale[t];
        u16* dst = tt.ing + tt.idstoff[t];
        for (int i = threadIdx.x; i < n; i += 256) {
            float v = m ? ((const float*)tt.isrc[t])[i] : bf2f(((const u16*)tt.isrc[t])[i]);
            dst[i] = f2bf(v * sc);
        }
        return;
    }
    __shared__ u16 tile[32][33];
    int wgt = 0;
#pragma unroll
    for (int i = 1; i < 7; ++i) if (bx >= tt.tstart[i]) wgt = i;
    int local = bx - tt.tstart[wgt];
    int K = tt.K[wgt], N = tt.N[wgt];
    float sc = tt.scale[wgt];
    int ntx = N >> 5;
    int txt = local % ntx, tyt = local / ntx;
    const void* W = tt.src[wgt];
    u16* Wt = tt.dst[wgt];
    int tx = threadIdx.x & 31, ty = threadIdx.x >> 5;
    int n = txt * 32 + tx;
    for (int i = ty; i < 32; i += 8) {
        size_t idx = (size_t)(tyt * 32 + i) * N + n;
        float v = m ? ((const float*)W)[idx] : bf2f(((const u16*)W)[idx]);
        tile[i][tx] = f2bf(v * sc);
    }
    __syncthreads();
    int k2 = tyt * 32 + tx;
    for (int i = ty; i < 32; i += 8) {
        int n2 = txt * 32 + i;
        Wt[(size_t)n2 * K + k2] = tile[tx][i];
    }
}

// ---------------- MFMA GEMM 64x128, BK=64 (QKV; vt epilogue) ---------------
__global__ __launch_bounds__(256) void k_gemm64(const u16* __restrict__ A,
                                                const u16* __restrict__ Bt,
                                                const u16* __restrict__ bias,
                                                u16* __restrict__ C,
                                                int N, int K, int relu,
                                                int gx, int mtpx,
                                                u16* __restrict__ vt) {
    __shared__ u16 As0[64][32], As1[64][32];
    __shared__ u16 Bs0[128][32], Bs1[128][32];
    const int tid = threadIdx.x;
    const int xcd = blockIdx.x & 7, j = blockIdx.x >> 3;
    const int m0 = (xcd * mtpx + j / gx) * 64, n0 = (j % gx) * 128;
    const int vmode = (vt != nullptr) && (n0 >= 512);
    const int lane = tid & 63, wid = tid >> 6;
    const int wm = (wid & 1) * 32, wn = (wid >> 1) * 64;
    const int m16 = lane & 15, quad = lane >> 4;
    f32x4 acc[2][4] = {};
    const int arow = tid >> 2;
    const int ac8  = (tid & 3) * 8;
    const u16* Ap  = A  + (size_t)(m0 + arow) * K + ac8;
    const u16* Bp0 = Bt + (size_t)(n0 + arow) * K + ac8;
    const u16* Bp1 = Bt + (size_t)(n0 + 64 + arow) * K + ac8;
    u16* lA0  = &As0[arow][ac8];
    u16* lA1  = &As1[arow][ac8];
    u16* lB00 = &Bs0[arow][ac8];
    u16* lB01 = &Bs0[64 + arow][ac8];
    u16* lB10 = &Bs1[arow][ac8];
    u16* lB11 = &Bs1[64 + arow][ac8];

    for (int k0 = 0; k0 < K; k0 += 64) {
        __syncthreads();
        gll16(Ap + k0,        lA0);
        gll16(Ap + k0 + 32,   lA1);
        gll16(Bp0 + k0,       lB00);
        gll16(Bp0 + k0 + 32,  lB10);
        gll16(Bp1 + k0,       lB01);
        gll16(Bp1 + k0 + 32,  lB11);
        __syncthreads();
#pragma unroll
        for (int ks = 0; ks < 2; ++ks) {
            bf16x8 af[2], bfv[4];
#pragma unroll
            for (int i = 0; i < 2; ++i)
                af[i] = ks == 0 ? *(const bf16x8*)&As0[wm + i * 16 + m16][quad * 8]
                                : *(const bf16x8*)&As1[wm + i * 16 + m16][quad * 8];
#pragma unroll
            for (int j2 = 0; j2 < 4; ++j2)
                bfv[j2] = ks == 0 ? *(const bf16x8*)&Bs0[wn + j2 * 16 + m16][quad * 8]
                                  : *(const bf16x8*)&Bs1[wn + j2 * 16 + m16][quad * 8];
#pragma unroll
            for (int i = 0; i < 2; ++i)
#pragma unroll
                for (int j2 = 0; j2 < 4; ++j2)
                    acc[i][j2] = __builtin_amdgcn_mfma_f32_16x16x32_bf16(
                        af[i], bfv[j2], acc[i][j2], 0, 0, 0);
        }
    }

#pragma unroll
    for (int i = 0; i < 2; ++i) {
        int row = m0 + wm + i * 16 + quad * 4;
#pragma unroll
        for (int j2 = 0; j2 < 4; ++j2) {
            int col = n0 + wn + j2 * 16 + m16;
            float bv = bf2f(bias[col]);
            if (vmode) {
                int ch = col - 512;
                u16x4 o;
#pragma unroll
                for (int r = 0; r < 4; ++r) o[r] = f2bf_fast(acc[i][j2][r] + bv);
                size_t vb = ((size_t)((row >> 10) * 4 + (ch >> 6)) * 64 + (ch & 63)) * 1024
                          + (row & 1023);
                *(u16x4*)&vt[vb] = o;
            } else {
#pragma unroll
                for (int r = 0; r < 4; ++r) {
                    float v = acc[i][j2][r] + bv;
                    if (relu) v = fmaxf(v, 0.f);
                    C[(size_t)(row + r) * N + col] = f2bf_fast(v);
                }
            }
        }
    }
}

// ---------------------------------------------------------------------------
// r24: fused FFN — FFO = relu(Y1@W1+b1)@W2+b2, Hb never materialized.
// 256 blocks x 64 rows. Y1 tile register-cached (reused over 32 chunks).
// Per chunk: stage W1[64 dff][256] + W2[256][64 k] (double-buffered, overlap
// with compute); GEMM1 swapped-MFMA -> lane holds H[row][4 contiguous dff]
// -> u16x4 writes to Hs[64][68] (bf16-quantized = old Hb values); GEMM2
// accumulates FFO[64x256] in regs over k ascending (same chain as old pair).
// LDS 136.5KB, 1 block/CU. Wave w: rw=w&1 row-half, dh=w>>1 dff/col-half.
// ---------------------------------------------------------------------------
__global__ __launch_bounds__(256) void k_ffn(const u16* __restrict__ Y1,
                                             const u16* __restrict__ W1t,
                                             const u16* __restrict__ b1,
                                             const u16* __restrict__ W2t,
                                             const u16* __restrict__ b2,
                                             u16* __restrict__ FFO) {
    __shared__ u16 W1s[2][8][64][32];    // [buf][kslice][dff-local][k32]
    __shared__ u16 W2s[2][2][256][32];   // [buf][ks][n][k32]
    __shared__ u16 Hs[64][68];           // pad 68 -> row stride 34 dwords
    const int tid = threadIdx.x, lane = tid & 63, w = tid >> 6;
    const int m16 = lane & 15, quad = lane >> 4;
    const int rw = w & 1, dh = w >> 1;
    const int xcd = blockIdx.x & 7, j = blockIdx.x >> 3;
    const int m0 = (xcd * 32 + j) * 64;
    const int arow = tid >> 2, ac8 = (tid & 3) * 8;

    // stage Y1 tile into W2s[0] area (flat 32KB), pull to registers
    u16* yb = &W2s[0][0][0][0];
#pragma unroll
    for (int s = 0; s < 8; ++s)
        gll16(Y1 + (size_t)(m0 + arow) * 256 + s * 32 + ac8, yb + s * 4096 + arow * 32 + ac8);
    __syncthreads();
    bf16x8 y1r[8][2];
#pragma unroll
    for (int s = 0; s < 8; ++s)
#pragma unroll
        for (int rt = 0; rt < 2; ++rt)
            y1r[s][rt] = *(const bf16x8*)&yb[s * 4096 + (rw * 32 + rt * 16 + m16) * 32 + quad * 8];
    __syncthreads();

#define FFN_STAGE(buf, c) do {                                                     \
    _Pragma("unroll")                                                              \
    for (int s = 0; s < 8; ++s)                                                    \
        gll16(W1t + (size_t)((c) * 64 + arow) * 256 + s * 32 + ac8,                \
              &W1s[buf][s][arow][ac8]);                                            \
    _Pragma("unroll")                                                              \
    for (int ks = 0; ks < 2; ++ks)                                                 \
        _Pragma("unroll")                                                          \
        for (int i = 0; i < 4; ++i) {                                              \
            int idx = i * 256 + tid;                                               \
            int n = idx >> 2, k8 = (idx & 3) * 8;                                  \
            gll16(W2t + (size_t)n * 2048 + (c) * 64 + ks * 32 + k8,                \
                  &W2s[buf][ks][n][k8]);                                           \
        }                                                                          \
} while (0)

    FFN_STAGE(0, 0);
    f32x4 acc2[2][8] = {};

    for (int c = 0; c < 32; ++c) {
        const int buf = c & 1;
        __syncthreads();                       // drains W(c) DMA; Hs free
        if (c + 1 < 32) FFN_STAGE(buf ^ 1, c + 1);
        float b1v[2][4];
#pragma unroll
        for (int dt = 0; dt < 2; ++dt)
#pragma unroll
            for (int r = 0; r < 4; ++r)
                b1v[dt][r] = bf2f(b1[c * 64 + dh * 32 + dt * 16 + quad * 4 + r]);
        // GEMM1 (swapped): lane -> H[rw*32+rt*16+m16][dh*32+dt*16+quad*4+r]
        f32x4 acc1[2][2] = {};
#pragma unroll
        for (int s = 0; s < 8; ++s) {
#pragma unroll
            for (int dt = 0; dt < 2; ++dt) {
                bf16x8 af = *(const bf16x8*)&W1s[buf][s][dh * 32 + dt * 16 + m16][quad * 8];
#pragma unroll
                for (int rt = 0; rt < 2; ++rt)
                    acc1[dt][rt] = __builtin_amdgcn_mfma_f32_16x16x32_bf16(
                        af, y1r[s][rt], acc1[dt][rt], 0, 0, 0);
            }
        }
#pragma unroll
        for (int dt = 0; dt < 2; ++dt)
#pragma unroll
            for (int rt = 0; rt < 2; ++rt) {
                u16x4 h4;
#pragma unroll
                for (int r = 0; r < 4; ++r)
                    h4[r] = f2bf_fast(fmaxf(acc1[dt][rt][r] + b1v[dt][r], 0.f));
                *(u16x4*)&Hs[rw * 32 + rt * 16 + m16][dh * 32 + dt * 16 + quad * 4] = h4;
            }
        __syncthreads();                       // Hs visible
        // GEMM2: FFO rows rw*32.., cols dh*128.. ; k ascending
#pragma unroll
        for (int ks = 0; ks < 2; ++ks) {
            bf16x8 af2[2];
#pragma unroll
            for (int rt = 0; rt < 2; ++rt)
                af2[rt] = *(const bf16x8*)&Hs[rw * 32 + rt * 16 + m16][ks * 32 + quad * 8];
#pragma unroll
            for (int ct = 0; ct < 8; ++ct) {
                bf16x8 bv = *(const bf16x8*)&W2s[buf][ks][dh * 128 + ct * 16 + m16][quad * 8];
#pragma unroll
                for (int rt = 0; rt < 2; ++rt)
                    acc2[rt][ct] = __builtin_amdgcn_mfma_f32_16x16x32_bf16(
                        af2[rt], bv, acc2[rt][ct], 0, 0, 0);
            }
        }
    }
#undef FFN_STAGE

#pragma unroll
    for (int ct = 0; ct < 8; ++ct) {
        int col = dh * 128 + ct * 16 + m16;
        float bv = bf2f(b2[col]);
#pragma unroll
        for (int rt = 0; rt < 2; ++rt) {
            int row = m0 + rw * 32 + rt * 16 + quad * 4;
#pragma unroll
            for (int r = 0; r < 4; ++r)
                FFO[(size_t)(row + r) * 256 + col] = f2bf_fast(acc2[rt][ct][r] + bv);
        }
    }
}

// ---------------------------------------------------------------------------
// r22: fused Wo-GEMM + residual + LayerNorm1 (validated). 16x256 tile/block.
// ---------------------------------------------------------------------------
__global__ __launch_bounds__(256) void k_wo_ln(const u16* __restrict__ A,
                                               const u16* __restrict__ Bt,
                                               const u16* __restrict__ bias,
                                               const u16* __restrict__ X,
                                               const u16* __restrict__ g,
                                               const u16* __restrict__ be,
                                               u16* __restrict__ Y1) {
    __shared__ u16 As0[16][32], As1[16][32];
    __shared__ u16 Bs0[256][32], Bs1[256][32];
    __shared__ float lnp[2][4][16];
    const int tid = threadIdx.x, lane = tid & 63, w = tid >> 6;
    const int m16 = lane & 15, quad = lane >> 4;
    const int xcd = blockIdx.x & 7, j = blockIdx.x >> 3;
    const int m0 = (xcd * 128 + j) * 16;
    const int K = 256;
    f32x4 acc[4] = {};
    const int an = lane >> 2, ac = (lane & 3) * 8;

    for (int k0 = 0; k0 < K; k0 += 64) {
        __syncthreads();
#pragma unroll
        for (int i = 0; i < 4; ++i) {
            int ch = i * 256 + tid;
            int n = ch >> 2, kc = (ch & 3) * 8;
            gll16(Bt + (size_t)n * K + k0 + kc,      &Bs0[n][kc]);
            gll16(Bt + (size_t)n * K + k0 + 32 + kc, &Bs1[n][kc]);
        }
        if (w == 0) gll16(A + (size_t)(m0 + an) * K + k0 + ac,      &As0[an][ac]);
        if (w == 1) gll16(A + (size_t)(m0 + an) * K + k0 + 32 + ac, &As1[an][ac]);
        __syncthreads();
#pragma unroll
        for (int ks = 0; ks < 2; ++ks) {
            bf16x8 af = ks == 0 ? *(const bf16x8*)&As0[m16][quad * 8]
                                : *(const bf16x8*)&As1[m16][quad * 8];
#pragma unroll
            for (int nt = 0; nt < 4; ++nt) {
                bf16x8 bfv = ks == 0
                    ? *(const bf16x8*)&Bs0[w * 64 + nt * 16 + m16][quad * 8]
                    : *(const bf16x8*)&Bs1[w * 64 + nt * 16 + m16][quad * 8];
                acc[nt] = __builtin_amdgcn_mfma_f32_16x16x32_bf16(af, bfv, acc[nt], 0, 0, 0);
            }
        }
    }

    float vln[4][4];
    float s[4] = {0.f, 0.f, 0.f, 0.f}, sq[4] = {0.f, 0.f, 0.f, 0.f};
#pragma unroll
    for (int nt = 0; nt < 4; ++nt) {
        int col = w * 64 + nt * 16 + m16;
        float bv = bf2f(bias[col]);
#pragma unroll
        for (int r = 0; r < 4; ++r) {
            int row = m0 + quad * 4 + r;
            u16 c16 = f2bf_fast(acc[nt][r] + bv);
            float v = bf2f(c16) + bf2f(X[(size_t)row * 256 + col]);
            vln[nt][r] = v;
            s[r] += v; sq[r] += v * v;
        }
    }
#pragma unroll
    for (int r = 0; r < 4; ++r)
        for (int off = 1; off < 16; off <<= 1) {
            s[r]  += __shfl_xor(s[r], off);
            sq[r] += __shfl_xor(sq[r], off);
        }
    if (m16 == 0) {
#pragma unroll
        for (int r = 0; r < 4; ++r) {
            lnp[0][w][quad * 4 + r] = s[r];
            lnp[1][w][quad * 4 + r] = sq[r];
        }
    }
    __syncthreads();
#pragma unroll
    for (int r = 0; r < 4; ++r) {
        int rw = quad * 4 + r;
        float st  = lnp[0][0][rw] + lnp[0][1][rw] + lnp[0][2][rw] + lnp[0][3][rw];
        float sqt = lnp[1][0][rw] + lnp[1][1][rw] + lnp[1][2][rw] + lnp[1][3][rw];
        float mean = st * (1.f / 256.f);
        float var  = sqt * (1.f / 256.f) - mean * mean;
        float rs   = rsqrtf(var + 1e-5f);
        int row = m0 + rw;
#pragma unroll
        for (int nt = 0; nt < 4; ++nt) {
            int col = w * 64 + nt * 16 + m16;
            Y1[(size_t)row * 256 + col] =
                f2bf((vln[nt][r] - mean) * rs * bf2f(g[col]) + bf2f(be[col]));
        }
    }
}

// ---------------------------------------------------------------------------
// r23: fused predicate head — 64x256-tile GEMM (relu(means@Wp1+bp1)) with
// in-block Wp2 dot + sigmoid + per-block comp partials.
// ---------------------------------------------------------------------------
__global__ __launch_bounds__(256) void k_predhead(const u16* __restrict__ A,
                                                  const u16* __restrict__ Bt,
                                                  const u16* __restrict__ bp1,
                                                  const u16* __restrict__ Wp2,
                                                  const u16* __restrict__ bp2,
                                                  const u16* __restrict__ wc,
                                                  const u16* __restrict__ bc,
                                                  const float* __restrict__ cnt,
                                                  float* __restrict__ predp) {
    const int tid = threadIdx.x;
    const int m0 = blockIdx.x * 64;
    if (cnt[m0] == 0.f) {
        if (tid == 0) { predp[2 * blockIdx.x] = 0.f; predp[2 * blockIdx.x + 1] = 0.f; }
        return;
    }
    __shared__ u16 As0[64][32], As1[64][32];
    __shared__ u16 Bs0[256][32], Bs1[256][32];
    __shared__ float cs[4], vs[4];
    const int lane = tid & 63, w = tid >> 6;
    const int m16 = lane & 15, quad = lane >> 4;
    f32x4 acc[16] = {};
    const int ar = tid >> 2, akc = (tid & 3) * 8;

    for (int k0 = 0; k0 < 256; k0 += 64) {
        __syncthreads();
        gll16(A + (size_t)(m0 + ar) * 256 + k0 + akc,      &As0[ar][akc]);
        gll16(A + (size_t)(m0 + ar) * 256 + k0 + 32 + akc, &As1[ar][akc]);
#pragma unroll
        for (int i = 0; i < 4; ++i) {
            int ch = i * 256 + tid;
            int n = ch >> 2, kc = (ch & 3) * 8;
            gll16(Bt + (size_t)n * 256 + k0 + kc,      &Bs0[n][kc]);
            gll16(Bt + (size_t)n * 256 + k0 + 32 + kc, &Bs1[n][kc]);
        }
        __syncthreads();
#pragma unroll
        for (int ks = 0; ks < 2; ++ks) {
            bf16x8 af = ks == 0 ? *(const bf16x8*)&As0[w * 16 + m16][quad * 8]
                                : *(const bf16x8*)&As1[w * 16 + m16][quad * 8];
#pragma unroll
            for (int nt = 0; nt < 16; ++nt) {
                bf16x8 bfv = ks == 0 ? *(const bf16x8*)&Bs0[nt * 16 + m16][quad * 8]
                                     : *(const bf16x8*)&Bs1[nt * 16 + m16][quad * 8];
                acc[nt] = __builtin_amdgcn_mfma_f32_16x16x32_bf16(af, bfv, acc[nt], 0, 0, 0);
            }
        }
    }

    const float fb = bf2f(bp2[0]), fw = bf2f(wc[0]), fc = bf2f(bc[0]);
    float part[4] = {0.f, 0.f, 0.f, 0.f};
#pragma unroll
    for (int nt = 0; nt < 16; ++nt) {
        int col = nt * 16 + m16;
        float bv = bf2f(bp1[col]);
        float wp = bf2f(Wp2[col]);
#pragma unroll
        for (int r = 0; r < 4; ++r) {
            float t = fmaxf(acc[nt][r] + bv, 0.f);
            part[r] += bf2f(f2bf_fast(t)) * wp;   // replicate TB bf16 round-trip
        }
    }
#pragma unroll
    for (int r = 0; r < 4; ++r)
        for (int off = 1; off < 16; off <<= 1)
            part[r] += __shfl_xor(part[r], off);

    float csum = 0.f, vsum = 0.f;
    if (m16 == 0) {
#pragma unroll
        for (int r = 0; r < 4; ++r) {
            int row = m0 + w * 16 + quad * 4 + r;
            if (cnt[row] > 0.f) {
                float pred = 1.f / (1.f + __expf(-(part[r] + fb)));
                csum += pred * fw + fc;
                vsum += 1.f;
            }
        }
    }
    csum += __shfl_xor(csum, 16); csum += __shfl_xor(csum, 32);
    vsum += __shfl_xor(vsum, 16); vsum += __shfl_xor(vsum, 32);
    if (lane == 0) { cs[w] = csum; vs[w] = vsum; }
    __syncthreads();
    if (tid == 0) {
        predp[2 * blockIdx.x]     = cs[0] + cs[1] + cs[2] + cs[3];
        predp[2 * blockIdx.x + 1] = vs[0] + vs[1] + vs[2] + vs[3];
    }
}

// ---------------------------------------------------------------------------
// MFMA flash attention — r19: double-buffered K/V tiles + register prefetch
// (T14). In-register P via swapped QK^T (mfma(K,Q)) + key-slot permutation;
// K stored at bit2<->bit3-swapped rows. 36.9KB LDS, 4 blocks/CU, 1024 blocks.
// ---------------------------------------------------------------------------
__global__ __launch_bounds__(256) void k_attn_mfma(const u16* __restrict__ QKV,
                                                   const u16* __restrict__ VT,
                                                   u16* __restrict__ CTX) {
    __shared__ u16 Ks[2][64][72];
    __shared__ u16 Vts[2][64][72];
    const int tid = threadIdx.x, lane = tid & 63, w = tid >> 6;
    const int quad = lane >> 4, c = lane & 15;
    const int blk = blockIdx.x;
    const int xcd = blk & 7, local = blk >> 3;
    const int bh = xcd * 8 + (local >> 4);
    const int qt = local & 15;
    const int b = bh >> 2, h = bh & 3;
    const int qrow0 = b * 1024 + qt * 64;

    const u16* qptr = QKV + (size_t)(qrow0 + w * 16 + c) * 768 + h * 64;
    bf16x8 aq0 = *(const bf16x8*)(qptr + quad * 8);
    bf16x8 aq1 = *(const bf16x8*)(qptr + 32 + quad * 8);

    bf16x8 ones;
    {
        union { u16 u; __bf16 h; } v; v.u = 0x3F80;
#pragma unroll
        for (int e = 0; e < 8; ++e) ones[e] = v.h;
    }

    f32x4 acc_o[4] = {};
    f32x4 acc_l = {};

    const u16* kbase  = QKV + (size_t)(b * 1024) * 768 + 256 + h * 64;
    const u16* vtbase = VT + (size_t)(bh * 64) * 1024;
    const int skk = tid >> 3, sc8 = (tid & 7) * 8;
    const int swk = (skk & ~12) | ((skk & 4) << 1) | ((skk & 8) >> 1);
    const int sra = ((c & 8) << 1) | (c & 4) | (c & 3);

    u16x8 rk0, rk1, rv0, rv1;

#define LOADT(t) do {                                                          \
    rk0 = *(const u16x8*)(kbase + (size_t)((t) * 64 + skk) * 768 + sc8);       \
    rk1 = *(const u16x8*)(kbase + (size_t)((t) * 64 + skk + 32) * 768 + sc8);  \
    rv0 = *(const u16x8*)(vtbase + (size_t)skk * 1024 + (t) * 64 + sc8);       \
    rv1 = *(const u16x8*)(vtbase + (size_t)(skk + 32) * 1024 + (t) * 64 + sc8);\
} while (0)

#define STORET(bi) do {                                                        \
    *(u16x8*)&Ks[bi][swk][sc8]       = rk0;                                    \
    *(u16x8*)&Ks[bi][swk + 32][sc8]  = rk1;                                    \
    *(u16x8*)&Vts[bi][skk][sc8]      = rv0;                                    \
    *(u16x8*)&Vts[bi][skk + 32][sc8] = rv1;                                    \
} while (0)

#define COMPUTE(bi) do {                                                        \
    _Pragma("unroll")                                                           \
    for (int ks = 0; ks < 2; ++ks) {                                            \
        const int ra = ks * 32 + sra;                                           \
        bf16x8 ka0 = *(const bf16x8*)&Ks[bi][ra][quad * 8];                     \
        bf16x8 ka1 = *(const bf16x8*)&Ks[bi][ra][32 + quad * 8];                \
        bf16x8 kb0 = *(const bf16x8*)&Ks[bi][ra + 8][quad * 8];                 \
        bf16x8 kb1 = *(const bf16x8*)&Ks[bi][ra + 8][32 + quad * 8];            \
        f32x4 za = {}, zb = {};                                                 \
        za = __builtin_amdgcn_mfma_f32_16x16x32_bf16(ka0, aq0, za, 0, 0, 0);    \
        za = __builtin_amdgcn_mfma_f32_16x16x32_bf16(ka1, aq1, za, 0, 0, 0);    \
        zb = __builtin_amdgcn_mfma_f32_16x16x32_bf16(kb0, aq0, zb, 0, 0, 0);    \
        zb = __builtin_amdgcn_mfma_f32_16x16x32_bf16(kb1, aq1, zb, 0, 0, 0);    \
        bf16x8 ap;                                                              \
        _Pragma("unroll")                                                       \
        for (int r = 0; r < 4; ++r) {                                           \
            ap[r]     = (__bf16)exp2f(fminf(za[r], 80.f));                      \
            ap[4 + r] = (__bf16)exp2f(fminf(zb[r], 80.f));                      \
        }                                                                       \
        acc_l = __builtin_amdgcn_mfma_f32_16x16x32_bf16(ap, ones, acc_l, 0, 0, 0);\
        _Pragma("unroll")                                                       \
        for (int nt = 0; nt < 4; ++nt) {                                        \
            bf16x8 bv = *(const bf16x8*)&Vts[bi][nt * 16 + c][ks * 32 + quad * 8];\
            acc_o[nt] = __builtin_amdgcn_mfma_f32_16x16x32_bf16(ap, bv, acc_o[nt], 0, 0, 0);\
        }                                                                       \
    }                                                                           \
} while (0)

    LOADT(0);
    STORET(0);
    for (int t = 0; t < 16; t += 2) {
        __syncthreads();
        LOADT(t + 1);
        COMPUTE(0);
        STORET(1);
        __syncthreads();
        if (t + 2 < 16) LOADT(t + 2);
        COMPUTE(1);
        if (t + 2 < 16) STORET(0);
    }

#undef LOADT
#undef STORET
#undef COMPUTE

#pragma unroll
    for (int nt = 0; nt < 4; ++nt) {
        int col = h * 64 + nt * 16 + c;
#pragma unroll
        for (int r = 0; r < 4; ++r) {
            int row = qrow0 + w * 16 + quad * 4 + r;
            CTX[(size_t)row * 256 + col] = f2bf_fast(acc_o[nt][r] / acc_l[r]);
        }
    }
}

// ---------------- LN2 + logits / KL / flags fused (KL partials) ------------
__global__ __launch_bounds__(256) void k_logits(const u16* __restrict__ FFO,
                                                const u16* __restrict__ Y1,
                                                const u16* __restrict__ g2,
                                                const u16* __restrict__ be2,
                                                const u16* __restrict__ Wl,
                                                const u16* __restrict__ bl,
                                                u16* __restrict__ Y2,
                                                float* __restrict__ klpart,
                                                int* __restrict__ flags) {
    const int tid = threadIdx.x, lane = tid & 63, w = tid >> 6;
    float wv[4][3], gv[4], bev[4];
#pragma unroll
    for (int j = 0; j < 4; ++j) {
        int d = lane * 4 + j;
        gv[j]  = bf2f(g2[d]);
        bev[j] = bf2f(be2[d]);
#pragma unroll
        for (int c = 0; c < 3; ++c) wv[j][c] = bf2f(Wl[d * 3 + c]);
    }
    const float b0 = bf2f(bl[0]), b1 = bf2f(bl[1]), b2 = bf2f(bl[2]);
    float klsum = 0.f;
    const int row0 = blockIdx.x * 16 + w * 4;
    for (int i = 0; i < 4; ++i) {
        int row = row0 + i;
        size_t base = (size_t)row * 256 + lane * 4;
        u16x4 f4 = *(const u16x4*)&FFO[base];
        u16x4 y4 = *(const u16x4*)&Y1[base];
        float v[4];
        float s = 0.f, sq = 0.f;
#pragma unroll
        for (int j = 0; j < 4; ++j) {
            v[j] = bf2f(f4[j]) + bf2f(y4[j]);
            s += v[j]; sq += v[j] * v[j];
        }
        for (int off = 32; off >= 1; off >>= 1) { s += __shfl_xor(s, off); sq += __shfl_xor(sq, off); }
        float mean = s * (1.f / 256.f);
        float var  = sq * (1.f / 256.f) - mean * mean;
        float rs   = rsqrtf(var + 1e-5f);
        u16x4 o;
        float a0 = 0.f, a1 = 0.f, a2 = 0.f;
#pragma unroll
        for (int j = 0; j < 4; ++j) {
            float yn = (v[j] - mean) * rs * gv[j] + bev[j];
            o[j] = f2bf(yn);
            float y = bf2f(o[j]);
            a0 += y * wv[j][0]; a1 += y * wv[j][1]; a2 += y * wv[j][2];
        }
        *(u16x4*)&Y2[base] = o;
        for (int off = 32; off >= 1; off >>= 1) {
            a0 += __shfl_xor(a0, off); a1 += __shfl_xor(a1, off); a2 += __shfl_xor(a2, off);
        }
        if (lane == 0) {
            float l0 = a0 + b0, l1 = a1 + b1, l2 = a2 + b2;
            float mx = fmaxf(l0, fmaxf(l1, l2));
            float lse = mx + __logf(__expf(l0 - mx) + __expf(l1 - mx) + __expf(l2 - mx));
            klsum += lse - (l0 + l1 + l2) * (1.f / 3.f) - 1.0986122886681098f;
            int am = 0; float bv = l0;
            if (l1 > bv) { bv = l1; am = 1; }
            if (l2 > bv) { am = 2; }
            int l = row & 1023;
            flags[row] = (am == 0 && l != 0) ? 1 : 0;
        }
    }
    __shared__ float kls[4];
    if (lane == 0) kls[w] = klsum;
    __syncthreads();
    if (tid == 0) klpart[blockIdx.x] = kls[0] + kls[1] + kls[2] + kls[3];
}

// per-batch exclusive scan: wave shuffle-scan, 2 barriers
__global__ void k_scan(const int* __restrict__ flags, int* __restrict__ seg) {
    __shared__ int wsum[16];
    int b = blockIdx.x, t = threadIdx.x;
    int lane = t & 63, w = t >> 6;
    int f = flags[b * 1024 + t];
    int x = f;
#pragma unroll
    for (int off = 1; off < 64; off <<= 1) {
        int v = __shfl_up(x, off);
        if (lane >= off) x += v;
    }
    if (lane == 63) wsum[w] = x;
    __syncthreads();
    if (w == 0) {
        int s = (lane < 16) ? wsum[lane] : 0;
#pragma unroll
        for (int off = 1; off < 16; off <<= 1) {
            int v = __shfl_up(s, off);
            if (lane >= off) s += v;
        }
        if (lane < 16) wsum[lane] = s;
    }
    __syncthreads();
    int prefix = (w > 0) ? wsum[w - 1] : 0;
    seg[b * 1024 + t] = prefix + x - f;
}

// ---------------- segmean: one block per (b,s); binary-search the run ------
__global__ __launch_bounds__(64) void k_segmean(const u16* __restrict__ Y,
                                                const int* __restrict__ seg,
                                                u16* __restrict__ means,
                                                float* __restrict__ cnt) {
    int g = blockIdx.x, lane = threadIdx.x;
    int b = g >> 10, s = g & 1023;
    const int* sb = seg + b * 1024;
    int target = s + (lane & 1);
    int lo = 0, hi = 1024;
    while (lo < hi) {
        int mid = (lo + hi) >> 1;
        if (sb[mid] < target) lo = mid + 1; else hi = mid;
    }
    int start = __shfl(lo, 0);
    int end   = __shfl(lo, 1);
    int n = end - start;
    if (lane == 0) cnt[g] = (float)n;
    if (n <= 0) return;
    f32x4 acc = {};
    for (int row = start; row < end; ++row) {
        u16x4 y4 = *(const u16x4*)&Y[(size_t)(b * 1024 + row) * 256 + lane * 4];
        acc[0] += bf2f(y4[0]); acc[1] += bf2f(y4[1]);
        acc[2] += bf2f(y4[2]); acc[3] += bf2f(y4[3]);
    }
    float inv = 1.f / (float)n;
    u16x4 o;
#pragma unroll
    for (int j = 0; j < 4; ++j) o[j] = f2bf(acc[j] * inv);
    *(u16x4*)&means[(size_t)g * 256 + lane * 4] = o;
}

// ---------------- finalize: sum KL + pred partials, store ----------------
// predp has 256 entries (16 blocks per batch).
__global__ void k_final(const float* __restrict__ predp, const float* __restrict__ klp,
                        const int* __restrict__ detp, void* __restrict__ outv) {
    int t = threadIdx.x;   // 64
    float k = 0.f;
    for (int i = t; i < 1024; i += 64) k += klp[i];
    for (int off = 32; off >= 1; off >>= 1) k += __shfl_xor(k, off);
    float ktot = __shfl(k, 0);
    int batch = t >> 2, ch = t & 3;
    float c = 0.f, v = 0.f;
    for (int i = 0; i < 4; ++i) {
        int blk = batch * 16 + ch * 4 + i;
        c += predp[2 * blk];
        v += predp[2 * blk + 1];
    }
    c += __shfl_xor(c, 1); c += __shfl_xor(c, 2);
    v += __shfl_xor(v, 1); v += __shfl_xor(v, 2);
    int mode = get_mode(detp);
    if ((t & 3) == 0) {
        float d = v, nm = c;
        if (!(d > 0.f)) d = 1.f;
        if (isnan(nm) || isinf(nm)) nm = 0.f;
        float val = 1.f / (1.f + __expf(-nm / d));
        if (mode) ((float*)outv)[batch] = val;
        else      ((u16*)outv)[batch]   = f2bf(val);
    }
    if (t == 1) {
        float val = ktot * (1.f / 16.f);
        if (isnan(val) || isinf(val)) val = 0.f;
        if (mode) ((float*)outv)[16] = val;
        else      ((u16*)outv)[16]   = f2bf(val);
    }
}

// ---------------------------------------------------------------------------
extern "C" void kernel_launch(void* const* d_in, const int* in_sizes, int n_in,
                              void* d_out, int out_size, void* d_ws, size_t ws_size,
                              hipStream_t stream) {
    const int* shape_idxs = (const int*)d_in[0];
    const int* color_idxs = (const int*)d_in[1];
    char* ws = (char*)d_ws;
    const size_t MB = 1024 * 1024;

    if (ws_size < 90 * MB) {
        int wsMB = (int)(ws_size >> 20); if (wsMB > 250) wsMB = 250;
        k_sentinel_f32<<<1, 32, 0, stream>>>((float*)d_out, 200 + wsMB);
        return;
    }

    // ---- arena ----
    u16*   X     = (u16*)(ws);
    u16*   QKVb  = (u16*)(ws + 8 * MB);
    u16*   VT    = (u16*)(ws + 32 * MB);
    u16*   CTX   = (u16*)(ws + 40 * MB);
    u16*   Y1    = (u16*)(ws + 64 * MB);
    u16*   FFO   = (u16*)(ws + 72 * MB);
    u16*   Y2    = (u16*)(ws);
    u16*   MEANS = (u16*)(ws + 24 * MB);
    int*   FLAGS = (int*)(ws + 80 * MB);
    int*   SEG   = (int*)(ws + 80 * MB + 65536);
    float* CNT   = (float*)(ws + 80 * MB + 131072);
    float* KLP   = (float*)(ws + 80 * MB + 262144);
    float* PREDP = (float*)(ws + 80 * MB + 327680);
    u16*   W3T   = (u16*)(ws + 81 * MB);
    u16*   WoT   = (u16*)(ws + 81 * MB + 786432);
    u16*   Wp1T  = (u16*)(ws + 81 * MB + 917504);
    u16*   W1T   = (u16*)(ws + 82 * MB);
    u16*   W2T   = (u16*)(ws + 83 * MB);
    int*   DETP  = (int*)(ws + 84 * MB);
    u16*   ING   = (u16*)(ws + 85 * MB);

    const float QSCALE = 0.125f * 1.44269504f;

    // prep table: 7 transposes + 17 small-tensor ingests + 2048 embed blocks
    PrepTab tt;
    const void* tsrc[7] = {d_in[4], d_in[6], d_in[8], d_in[10], d_in[22], d_in[14], d_in[16]};
    u16* tdst[7] = {W3T, W3T + 256 * 256, W3T + 512 * 256, WoT, Wp1T, W1T, W2T};
    int tK[7] = {256, 256, 256, 256, 256, 256, 2048};
    int tN[7] = {256, 256, 256, 256, 256, 2048, 256};
    int ts = 0;
    for (int i = 0; i < 7; ++i) {
        tt.src[i] = tsrc[i]; tt.dst[i] = tdst[i]; tt.K[i] = tK[i]; tt.N[i] = tN[i];
        tt.scale[i] = (i == 0) ? QSCALE : 1.0f;
        tt.tstart[i] = ts;
        ts += (tK[i] >> 5) * (tN[i] >> 5);
    }
    tt.tstart[7] = ts;

    static const int II[17]  = {5, 7, 9, 11, 12, 13, 15, 17, 18, 19, 20, 21, 23, 24, 25, 26, 27};
    static const int IN[17]  = {256, 256, 256, 256, 256, 256, 2048, 256, 256, 256, 768, 3, 256, 256, 1, 1, 1};
    unsigned off = 0;
    for (int i = 0; i < 17; ++i) {
        tt.isrc[i] = d_in[II[i]];
        tt.in[i] = IN[i];
        tt.iscale[i] = 1.0f;
        if (i == 0) { tt.idstoff[0] = off; off += 768; }
        else if (i == 1) tt.idstoff[1] = tt.idstoff[0] + 256;
        else if (i == 2) tt.idstoff[2] = tt.idstoff[0] + 512;
        else { tt.idstoff[i] = off; off += (unsigned)((IN[i] + 8) & ~7); }
    }
    tt.iscale[0] = QSCALE;   // bq
    tt.ing = ING;
    tt.estart = ts + 17;
    tt.si = shape_idxs; tt.ci = color_idxs;
    tt.se = d_in[2]; tt.ce = d_in[3]; tt.X = X;
    const u16* ib3  = ING + tt.idstoff[0];
    const u16* ibo  = ING + tt.idstoff[3];
    const u16* ig1  = ING + tt.idstoff[4];  const u16* ibe1 = ING + tt.idstoff[5];
    const u16* ibf1 = ING + tt.idstoff[6];  const u16* ibf2 = ING + tt.idstoff[7];
    const u16* ig2  = ING + tt.idstoff[8];  const u16* ibe2 = ING + tt.idstoff[9];
    const u16* iWl  = ING + tt.idstoff[10]; const u16* ibl  = ING + tt.idstoff[11];
    const u16* ibp1 = ING + tt.idstoff[12]; const u16* iWp2 = ING + tt.idstoff[13];
    const u16* ibp2 = ING + tt.idstoff[14]; const u16* iwc  = ING + tt.idstoff[15];
    const u16* ibc  = ING + tt.idstoff[16];

    // 0) detect (plain partials)
    k_detect<<<64, 256, 0, stream>>>((const u16*)d_in[14], DETP);
    // 1) prep: transposes + small ingest + embedding, one launch
    k_prep<<<ts + 17 + 2048, 256, 0, stream>>>(tt, DETP);
    // 2) fused QKV projection; V columns written directly in VT layout
    k_gemm64<<<1536, 256, 0, stream>>>(X, W3T, ib3, QKVb, 768, 256, 0, 6, 32, VT);
    // 3) attention
    k_attn_mfma<<<1024, 256, 0, stream>>>(QKVb, VT, CTX);
    // 4) fused Wo GEMM + residual + LN1 -> Y1
    k_wo_ln<<<1024, 256, 0, stream>>>(CTX, WoT, ibo, X, ig1, ibe1, Y1);
    // 5) fused FFN (FFN1+FFN2, no Hb round-trip)
    k_ffn<<<256, 256, 0, stream>>>(Y1, W1T, ibf1, W2T, ibf2, FFO);
    // 6) LN2 + logits / KL / flags (fused; writes Y2, KL partials)
    k_logits<<<1024, 256, 0, stream>>>(FFO, Y1, ig2, ibe2, iWl, ibl, Y2, KLP, FLAGS);
    // 7) per-batch exclusive scan
    k_scan<<<16, 1024, 0, stream>>>(FLAGS, SEG);
    // 8) segment means
    k_segmean<<<16384, 64, 0, stream>>>(Y2, SEG, MEANS, CNT);
    // 9) fused predicate head (GEMM + Wp2 dot + sigmoid + partials)
    k_predhead<<<256, 256, 0, stream>>>(MEANS, Wp1T, ibp1, iWp2, ibp2, iwc, ibc, CNT, PREDP);
    // 10) finalize + store
    k_final<<<1, 64, 0, stream>>>(PREDP, KLP, DETP, d_out);
}

// Round 8
// 288.662 us; speedup vs baseline: 1.0364x; 1.0364x over previous
//
#include <hip/hip_runtime.h>

// ---------------------------------------------------------------------------
// B=16, L=1024, D=256, H=4 (DH=64), DFF=2048, C=3. Output: 17 elems.
// Dtype-adaptive (f32 or bf16 inputs; mode from DETP partial sums). Wq/bq
// pre-scaled by 0.125*log2e so attention softmax is bare exp2.
// r25: r24's k_ffn mega-fusion REVERTED (77.8us, 1 block/CU: 136KB LDS killed
// occupancy; 64 serial barriers with ~64KB staging vs 64 MFMA per chunk =
// naked latency. Lesson: fusion must preserve blocks/CU). FFN restored as
// two launches; FFN1 switched from k_gemm_bt (128-tile, 2048 blocks, VGPR 84,
// Occ 25%) to the validated k_gemm64n high-TLP structure: 8192 blocks =
// 32/CU queued, VGPR 32, 16KB LDS. Same K-ascending accumulation order ->
// bit-identical Hb. k_gemm_bt/k_ffn deleted. 12 launches.
// r23: prep+embed merge, predhead fusion. r22: k_wo_ln fusion.
// r19: attention dbuf K/V + register prefetch. r18: in-register P.
// ---------------------------------------------------------------------------

typedef unsigned short u16;
typedef u16    u16x4  __attribute__((ext_vector_type(4)));
typedef u16    u16x8  __attribute__((ext_vector_type(8)));
typedef __bf16 bf16x8 __attribute__((ext_vector_type(8)));
typedef float  f32x4  __attribute__((ext_vector_type(4)));

__device__ __forceinline__ float bf2f(u16 u) {
    union { unsigned int i; float f; } v; v.i = ((unsigned int)u) << 16; return v.f;
}
__device__ __forceinline__ u16 f2bf(float f) {
    union { float f; unsigned int i; } v; v.f = f;
    unsigned int r = (v.i + 0x7FFFu + ((v.i >> 16) & 1u)) >> 16;
    return (u16)r;
}
__device__ __forceinline__ u16 f2bf_fast(float f) {
    union { __bf16 h; u16 u; } v; v.h = (__bf16)f; return v.u;
}
__device__ __forceinline__ void gll16(const u16* g, u16* l) {
    __builtin_amdgcn_global_load_lds((__attribute__((address_space(1))) void*)(u16*)g,
                                     (__attribute__((address_space(3))) void*)l, 16, 0, 0);
}
__device__ __forceinline__ int get_mode(const int* __restrict__ detp) {
    int s = 0;
#pragma unroll 8
    for (int i = 0; i < 64; ++i) s += detp[i];
    return s > 16;
}

// ---------------- dtype detection: plain per-block partials ----------------
__global__ __launch_bounds__(256) void k_detect(const u16* __restrict__ w1raw,
                                                int* __restrict__ detp) {
    int i = blockIdx.x * 256 + threadIdx.x;
    int bad = 0;
    for (int k = i; k < 65536; k += 64 * 256) {
        unsigned v = w1raw[k] & 0x7FFFu;
        if (v >= 0x7F80u) bad++;
    }
    for (int off = 32; off >= 1; off >>= 1) bad += __shfl_xor(bad, off);
    __shared__ int bs[4];
    if ((threadIdx.x & 63) == 0) bs[threadIdx.x >> 6] = bad;
    __syncthreads();
    if (threadIdx.x == 0) detp[blockIdx.x] = bs[0] + bs[1] + bs[2] + bs[3];
}
__global__ void k_sentinel_f32(float* __restrict__ out, int code) {
    int t = threadIdx.x;
    if (t < 17) out[t] = (float)code;
}

// ------- prep: transposes + small ingest + embedding, one launch -----------
struct PrepTab {
    const void* src[7];
    u16*        dst[7];
    int         K[7], N[7];
    float       scale[7];
    int         tstart[8];     // transpose tile ranges; ingest = [tstart[7], +17)
    const void* isrc[17];
    unsigned    idstoff[17];
    int         in[17];
    float       iscale[17];
    u16*        ing;
    int         estart;        // embed blocks start here
    const int*  si;
    const int*  ci;
    const void* se;
    const void* ce;
    u16*        X;
};
__global__ __launch_bounds__(256) void k_prep(PrepTab tt, const int* __restrict__ detp) {
    int m = get_mode(detp);
    int bx = blockIdx.x;
    if (bx >= tt.estart) {                    // ---- embedding ----
        int t = (bx - tt.estart) * 256 + threadIdx.x;
        int row = t >> 5, seg = (t & 31) * 8;
        int s = tt.si[row], c = tt.ci[row];
        u16x8 o;
        if (m) {
            const float* sp = (const float*)tt.se + s * 256 + seg;
            const float* cp = (const float*)tt.ce + c * 256 + seg;
#pragma unroll
            for (int e = 0; e < 8; ++e) o[e] = f2bf(sp[e] + cp[e]);
        } else {
            u16x8 a = *(const u16x8*)((const u16*)tt.se + s * 256 + seg);
            u16x8 b = *(const u16x8*)((const u16*)tt.ce + c * 256 + seg);
#pragma unroll
            for (int e = 0; e < 8; ++e) o[e] = f2bf(bf2f(a[e]) + bf2f(b[e]));
        }
        *(u16x8*)&tt.X[(size_t)row * 256 + seg] = o;
        return;
    }
    if (bx >= tt.tstart[7]) {                 // ---- small-tensor ingest ----
        int t = bx - tt.tstart[7];
        int n = tt.in[t];
        float sc = tt.iscale[t];
        u16* dst = tt.ing + tt.idstoff[t];
        for (int i = threadIdx.x; i < n; i += 256) {
            float v = m ? ((const float*)tt.isrc[t])[i] : bf2f(((const u16*)tt.isrc[t])[i]);
            dst[i] = f2bf(v * sc);
        }
        return;
    }
    __shared__ u16 tile[32][33];
    int wgt = 0;
#pragma unroll
    for (int i = 1; i < 7; ++i) if (bx >= tt.tstart[i]) wgt = i;
    int local = bx - tt.tstart[wgt];
    int K = tt.K[wgt], N = tt.N[wgt];
    float sc = tt.scale[wgt];
    int ntx = N >> 5;
    int txt = local % ntx, tyt = local / ntx;
    const void* W = tt.src[wgt];
    u16* Wt = tt.dst[wgt];
    int tx = threadIdx.x & 31, ty = threadIdx.x >> 5;
    int n = txt * 32 + tx;
    for (int i = ty; i < 32; i += 8) {
        size_t idx = (size_t)(tyt * 32 + i) * N + n;
        float v = m ? ((const float*)W)[idx] : bf2f(((const u16*)W)[idx]);
        tile[i][tx] = f2bf(v * sc);
    }
    __syncthreads();
    int k2 = tyt * 32 + tx;
    for (int i = ty; i < 32; i += 8) {
        int n2 = txt * 32 + i;
        Wt[(size_t)n2 * K + k2] = tile[tx][i];
    }
}

// ---------------- MFMA GEMM 64x128, BK=64 (QKV; vt epilogue) ---------------
__global__ __launch_bounds__(256) void k_gemm64(const u16* __restrict__ A,
                                                const u16* __restrict__ Bt,
                                                const u16* __restrict__ bias,
                                                u16* __restrict__ C,
                                                int N, int K, int relu,
                                                int gx, int mtpx,
                                                u16* __restrict__ vt) {
    __shared__ u16 As0[64][32], As1[64][32];
    __shared__ u16 Bs0[128][32], Bs1[128][32];
    const int tid = threadIdx.x;
    const int xcd = blockIdx.x & 7, j = blockIdx.x >> 3;
    const int m0 = (xcd * mtpx + j / gx) * 64, n0 = (j % gx) * 128;
    const int vmode = (vt != nullptr) && (n0 >= 512);
    const int lane = tid & 63, wid = tid >> 6;
    const int wm = (wid & 1) * 32, wn = (wid >> 1) * 64;
    const int m16 = lane & 15, quad = lane >> 4;
    f32x4 acc[2][4] = {};
    const int arow = tid >> 2;
    const int ac8  = (tid & 3) * 8;
    const u16* Ap  = A  + (size_t)(m0 + arow) * K + ac8;
    const u16* Bp0 = Bt + (size_t)(n0 + arow) * K + ac8;
    const u16* Bp1 = Bt + (size_t)(n0 + 64 + arow) * K + ac8;
    u16* lA0  = &As0[arow][ac8];
    u16* lA1  = &As1[arow][ac8];
    u16* lB00 = &Bs0[arow][ac8];
    u16* lB01 = &Bs0[64 + arow][ac8];
    u16* lB10 = &Bs1[arow][ac8];
    u16* lB11 = &Bs1[64 + arow][ac8];

    for (int k0 = 0; k0 < K; k0 += 64) {
        __syncthreads();
        gll16(Ap + k0,        lA0);
        gll16(Ap + k0 + 32,   lA1);
        gll16(Bp0 + k0,       lB00);
        gll16(Bp0 + k0 + 32,  lB10);
        gll16(Bp1 + k0,       lB01);
        gll16(Bp1 + k0 + 32,  lB11);
        __syncthreads();
#pragma unroll
        for (int ks = 0; ks < 2; ++ks) {
            bf16x8 af[2], bfv[4];
#pragma unroll
            for (int i = 0; i < 2; ++i)
                af[i] = ks == 0 ? *(const bf16x8*)&As0[wm + i * 16 + m16][quad * 8]
                                : *(const bf16x8*)&As1[wm + i * 16 + m16][quad * 8];
#pragma unroll
            for (int j2 = 0; j2 < 4; ++j2)
                bfv[j2] = ks == 0 ? *(const bf16x8*)&Bs0[wn + j2 * 16 + m16][quad * 8]
                                  : *(const bf16x8*)&Bs1[wn + j2 * 16 + m16][quad * 8];
#pragma unroll
            for (int i = 0; i < 2; ++i)
#pragma unroll
                for (int j2 = 0; j2 < 4; ++j2)
                    acc[i][j2] = __builtin_amdgcn_mfma_f32_16x16x32_bf16(
                        af[i], bfv[j2], acc[i][j2], 0, 0, 0);
        }
    }

#pragma unroll
    for (int i = 0; i < 2; ++i) {
        int row = m0 + wm + i * 16 + quad * 4;
#pragma unroll
        for (int j2 = 0; j2 < 4; ++j2) {
            int col = n0 + wn + j2 * 16 + m16;
            float bv = bf2f(bias[col]);
            if (vmode) {
                int ch = col - 512;
                u16x4 o;
#pragma unroll
                for (int r = 0; r < 4; ++r) o[r] = f2bf_fast(acc[i][j2][r] + bv);
                size_t vb = ((size_t)((row >> 10) * 4 + (ch >> 6)) * 64 + (ch & 63)) * 1024
                          + (row & 1023);
                *(u16x4*)&vt[vb] = o;
            } else {
#pragma unroll
                for (int r = 0; r < 4; ++r) {
                    float v = acc[i][j2][r] + bv;
                    if (relu) v = fmaxf(v, 0.f);
                    C[(size_t)(row + r) * N + col] = f2bf_fast(v);
                }
            }
        }
    }
}

// ---------------- MFMA GEMM 64x64, BK=64 — high-TLP (FFN1, FFN2) -----------
// VGPR 32, LDS 16KB; grid = (M/64)*(N/64) blocks, XCD-banded. Used for both
// FFN1 (N=2048, 8192 blocks = 32/CU queued) and FFN2 (N=256, 1024 blocks).
__global__ __launch_bounds__(256) void k_gemm64n(const u16* __restrict__ A,
                                                 const u16* __restrict__ Bt,
                                                 const u16* __restrict__ bias,
                                                 u16* __restrict__ C,
                                                 int N, int K, int relu,
                                                 int gnx, int mtpx,
                                                 const float* __restrict__ gate) {
    __shared__ u16 As0[64][32], As1[64][32];
    __shared__ u16 Bs0[64][32], Bs1[64][32];
    const int tid = threadIdx.x;
    const int xcd = blockIdx.x & 7, j = blockIdx.x >> 3;
    const int m0 = (xcd * mtpx + j / gnx) * 64, n0 = (j % gnx) * 64;
    if (gate && gate[m0] == 0.f) return;
    const int lane = tid & 63, w = tid >> 6;
    const int m16 = lane & 15, quad = lane >> 4;
    f32x4 acc[4] = {};
    const int arow = tid >> 2;          // 0..63
    const int ac8  = (tid & 3) * 8;     // 0,8,16,24
    const u16* Ap = A  + (size_t)(m0 + arow) * K + ac8;
    const u16* Bp = Bt + (size_t)(n0 + arow) * K + ac8;
    u16* lA0 = &As0[arow][ac8];
    u16* lA1 = &As1[arow][ac8];
    u16* lB0 = &Bs0[arow][ac8];
    u16* lB1 = &Bs1[arow][ac8];

    for (int k0 = 0; k0 < K; k0 += 64) {
        __syncthreads();
        gll16(Ap + k0,       lA0);
        gll16(Ap + k0 + 32,  lA1);
        gll16(Bp + k0,       lB0);
        gll16(Bp + k0 + 32,  lB1);
        __syncthreads();
#pragma unroll
        for (int ks = 0; ks < 2; ++ks) {
            bf16x8 af = ks == 0 ? *(const bf16x8*)&As0[w * 16 + m16][quad * 8]
                                : *(const bf16x8*)&As1[w * 16 + m16][quad * 8];
#pragma unroll
            for (int nt = 0; nt < 4; ++nt) {
                bf16x8 bfv = ks == 0 ? *(const bf16x8*)&Bs0[nt * 16 + m16][quad * 8]
                                     : *(const bf16x8*)&Bs1[nt * 16 + m16][quad * 8];
                acc[nt] = __builtin_amdgcn_mfma_f32_16x16x32_bf16(af, bfv, acc[nt], 0, 0, 0);
            }
        }
    }

#pragma unroll
    for (int nt = 0; nt < 4; ++nt) {
        int col = n0 + nt * 16 + m16;
        float bv = bf2f(bias[col]);
        int row = m0 + w * 16 + quad * 4;
#pragma unroll
        for (int r = 0; r < 4; ++r) {
            float v = acc[nt][r] + bv;
            if (relu) v = fmaxf(v, 0.f);
            C[(size_t)(row + r) * N + col] = f2bf_fast(v);
        }
    }
}

// ---------------------------------------------------------------------------
// r22: fused Wo-GEMM + residual + LayerNorm1 (validated). 16x256 tile/block.
// ---------------------------------------------------------------------------
__global__ __launch_bounds__(256) void k_wo_ln(const u16* __restrict__ A,
                                               const u16* __restrict__ Bt,
                                               const u16* __restrict__ bias,
                                               const u16* __restrict__ X,
                                               const u16* __restrict__ g,
                                               const u16* __restrict__ be,
                                               u16* __restrict__ Y1) {
    __shared__ u16 As0[16][32], As1[16][32];
    __shared__ u16 Bs0[256][32], Bs1[256][32];
    __shared__ float lnp[2][4][16];
    const int tid = threadIdx.x, lane = tid & 63, w = tid >> 6;
    const int m16 = lane & 15, quad = lane >> 4;
    const int xcd = blockIdx.x & 7, j = blockIdx.x >> 3;
    const int m0 = (xcd * 128 + j) * 16;
    const int K = 256;
    f32x4 acc[4] = {};
    const int an = lane >> 2, ac = (lane & 3) * 8;

    for (int k0 = 0; k0 < K; k0 += 64) {
        __syncthreads();
#pragma unroll
        for (int i = 0; i < 4; ++i) {
            int ch = i * 256 + tid;
            int n = ch >> 2, kc = (ch & 3) * 8;
            gll16(Bt + (size_t)n * K + k0 + kc,      &Bs0[n][kc]);
            gll16(Bt + (size_t)n * K + k0 + 32 + kc, &Bs1[n][kc]);
        }
        if (w == 0) gll16(A + (size_t)(m0 + an) * K + k0 + ac,      &As0[an][ac]);
        if (w == 1) gll16(A + (size_t)(m0 + an) * K + k0 + 32 + ac, &As1[an][ac]);
        __syncthreads();
#pragma unroll
        for (int ks = 0; ks < 2; ++ks) {
            bf16x8 af = ks == 0 ? *(const bf16x8*)&As0[m16][quad * 8]
                                : *(const bf16x8*)&As1[m16][quad * 8];
#pragma unroll
            for (int nt = 0; nt < 4; ++nt) {
                bf16x8 bfv = ks == 0
                    ? *(const bf16x8*)&Bs0[w * 64 + nt * 16 + m16][quad * 8]
                    : *(const bf16x8*)&Bs1[w * 64 + nt * 16 + m16][quad * 8];
                acc[nt] = __builtin_amdgcn_mfma_f32_16x16x32_bf16(af, bfv, acc[nt], 0, 0, 0);
            }
        }
    }

    float vln[4][4];
    float s[4] = {0.f, 0.f, 0.f, 0.f}, sq[4] = {0.f, 0.f, 0.f, 0.f};
#pragma unroll
    for (int nt = 0; nt < 4; ++nt) {
        int col = w * 64 + nt * 16 + m16;
        float bv = bf2f(bias[col]);
#pragma unroll
        for (int r = 0; r < 4; ++r) {
            int row = m0 + quad * 4 + r;
            u16 c16 = f2bf_fast(acc[nt][r] + bv);
            float v = bf2f(c16) + bf2f(X[(size_t)row * 256 + col]);
            vln[nt][r] = v;
            s[r] += v; sq[r] += v * v;
        }
    }
#pragma unroll
    for (int r = 0; r < 4; ++r)
        for (int off = 1; off < 16; off <<= 1) {
            s[r]  += __shfl_xor(s[r], off);
            sq[r] += __shfl_xor(sq[r], off);
        }
    if (m16 == 0) {
#pragma unroll
        for (int r = 0; r < 4; ++r) {
            lnp[0][w][quad * 4 + r] = s[r];
            lnp[1][w][quad * 4 + r] = sq[r];
        }
    }
    __syncthreads();
#pragma unroll
    for (int r = 0; r < 4; ++r) {
        int rw = quad * 4 + r;
        float st  = lnp[0][0][rw] + lnp[0][1][rw] + lnp[0][2][rw] + lnp[0][3][rw];
        float sqt = lnp[1][0][rw] + lnp[1][1][rw] + lnp[1][2][rw] + lnp[1][3][rw];
        float mean = st * (1.f / 256.f);
        float var  = sqt * (1.f / 256.f) - mean * mean;
        float rs   = rsqrtf(var + 1e-5f);
        int row = m0 + rw;
#pragma unroll
        for (int nt = 0; nt < 4; ++nt) {
            int col = w * 64 + nt * 16 + m16;
            Y1[(size_t)row * 256 + col] =
                f2bf((vln[nt][r] - mean) * rs * bf2f(g[col]) + bf2f(be[col]));
        }
    }
}

// ---------------------------------------------------------------------------
// r23: fused predicate head — 64x256-tile GEMM (relu(means@Wp1+bp1)) with
// in-block Wp2 dot + sigmoid + per-block comp partials.
// ---------------------------------------------------------------------------
__global__ __launch_bounds__(256) void k_predhead(const u16* __restrict__ A,
                                                  const u16* __restrict__ Bt,
                                                  const u16* __restrict__ bp1,
                                                  const u16* __restrict__ Wp2,
                                                  const u16* __restrict__ bp2,
                                                  const u16* __restrict__ wc,
                                                  const u16* __restrict__ bc,
                                                  const float* __restrict__ cnt,
                                                  float* __restrict__ predp) {
    const int tid = threadIdx.x;
    const int m0 = blockIdx.x * 64;
    if (cnt[m0] == 0.f) {
        if (tid == 0) { predp[2 * blockIdx.x] = 0.f; predp[2 * blockIdx.x + 1] = 0.f; }
        return;
    }
    __shared__ u16 As0[64][32], As1[64][32];
    __shared__ u16 Bs0[256][32], Bs1[256][32];
    __shared__ float cs[4], vs[4];
    const int lane = tid & 63, w = tid >> 6;
    const int m16 = lane & 15, quad = lane >> 4;
    f32x4 acc[16] = {};
    const int ar = tid >> 2, akc = (tid & 3) * 8;

    for (int k0 = 0; k0 < 256; k0 += 64) {
        __syncthreads();
        gll16(A + (size_t)(m0 + ar) * 256 + k0 + akc,      &As0[ar][akc]);
        gll16(A + (size_t)(m0 + ar) * 256 + k0 + 32 + akc, &As1[ar][akc]);
#pragma unroll
        for (int i = 0; i < 4; ++i) {
            int ch = i * 256 + tid;
            int n = ch >> 2, kc = (ch & 3) * 8;
            gll16(Bt + (size_t)n * 256 + k0 + kc,      &Bs0[n][kc]);
            gll16(Bt + (size_t)n * 256 + k0 + 32 + kc, &Bs1[n][kc]);
        }
        __syncthreads();
#pragma unroll
        for (int ks = 0; ks < 2; ++ks) {
            bf16x8 af = ks == 0 ? *(const bf16x8*)&As0[w * 16 + m16][quad * 8]
                                : *(const bf16x8*)&As1[w * 16 + m16][quad * 8];
#pragma unroll
            for (int nt = 0; nt < 16; ++nt) {
                bf16x8 bfv = ks == 0 ? *(const bf16x8*)&Bs0[nt * 16 + m16][quad * 8]
                                     : *(const bf16x8*)&Bs1[nt * 16 + m16][quad * 8];
                acc[nt] = __builtin_amdgcn_mfma_f32_16x16x32_bf16(af, bfv, acc[nt], 0, 0, 0);
            }
        }
    }

    const float fb = bf2f(bp2[0]), fw = bf2f(wc[0]), fc = bf2f(bc[0]);
    float part[4] = {0.f, 0.f, 0.f, 0.f};
#pragma unroll
    for (int nt = 0; nt < 16; ++nt) {
        int col = nt * 16 + m16;
        float bv = bf2f(bp1[col]);
        float wp = bf2f(Wp2[col]);
#pragma unroll
        for (int r = 0; r < 4; ++r) {
            float t = fmaxf(acc[nt][r] + bv, 0.f);
            part[r] += bf2f(f2bf_fast(t)) * wp;   // replicate TB bf16 round-trip
        }
    }
#pragma unroll
    for (int r = 0; r < 4; ++r)
        for (int off = 1; off < 16; off <<= 1)
            part[r] += __shfl_xor(part[r], off);

    float csum = 0.f, vsum = 0.f;
    if (m16 == 0) {
#pragma unroll
        for (int r = 0; r < 4; ++r) {
            int row = m0 + w * 16 + quad * 4 + r;
            if (cnt[row] > 0.f) {
                float pred = 1.f / (1.f + __expf(-(part[r] + fb)));
                csum += pred * fw + fc;
                vsum += 1.f;
            }
        }
    }
    csum += __shfl_xor(csum, 16); csum += __shfl_xor(csum, 32);
    vsum += __shfl_xor(vsum, 16); vsum += __shfl_xor(vsum, 32);
    if (lane == 0) { cs[w] = csum; vs[w] = vsum; }
    __syncthreads();
    if (tid == 0) {
        predp[2 * blockIdx.x]     = cs[0] + cs[1] + cs[2] + cs[3];
        predp[2 * blockIdx.x + 1] = vs[0] + vs[1] + vs[2] + vs[3];
    }
}

// ---------------------------------------------------------------------------
// MFMA flash attention — r19: double-buffered K/V tiles + register prefetch
// (T14). In-register P via swapped QK^T (mfma(K,Q)) + key-slot permutation;
// K stored at bit2<->bit3-swapped rows. 36.9KB LDS, 4 blocks/CU, 1024 blocks.
// ---------------------------------------------------------------------------
__global__ __launch_bounds__(256) void k_attn_mfma(const u16* __restrict__ QKV,
                                                   const u16* __restrict__ VT,
                                                   u16* __restrict__ CTX) {
    __shared__ u16 Ks[2][64][72];
    __shared__ u16 Vts[2][64][72];
    const int tid = threadIdx.x, lane = tid & 63, w = tid >> 6;
    const int quad = lane >> 4, c = lane & 15;
    const int blk = blockIdx.x;
    const int xcd = blk & 7, local = blk >> 3;
    const int bh = xcd * 8 + (local >> 4);
    const int qt = local & 15;
    const int b = bh >> 2, h = bh & 3;
    const int qrow0 = b * 1024 + qt * 64;

    const u16* qptr = QKV + (size_t)(qrow0 + w * 16 + c) * 768 + h * 64;
    bf16x8 aq0 = *(const bf16x8*)(qptr + quad * 8);
    bf16x8 aq1 = *(const bf16x8*)(qptr + 32 + quad * 8);

    bf16x8 ones;
    {
        union { u16 u; __bf16 h; } v; v.u = 0x3F80;
#pragma unroll
        for (int e = 0; e < 8; ++e) ones[e] = v.h;
    }

    f32x4 acc_o[4] = {};
    f32x4 acc_l = {};

    const u16* kbase  = QKV + (size_t)(b * 1024) * 768 + 256 + h * 64;
    const u16* vtbase = VT + (size_t)(bh * 64) * 1024;
    const int skk = tid >> 3, sc8 = (tid & 7) * 8;
    const int swk = (skk & ~12) | ((skk & 4) << 1) | ((skk & 8) >> 1);
    const int sra = ((c & 8) << 1) | (c & 4) | (c & 3);

    u16x8 rk0, rk1, rv0, rv1;

#define LOADT(t) do {                                                          \
    rk0 = *(const u16x8*)(kbase + (size_t)((t) * 64 + skk) * 768 + sc8);       \
    rk1 = *(const u16x8*)(kbase + (size_t)((t) * 64 + skk + 32) * 768 + sc8);  \
    rv0 = *(const u16x8*)(vtbase + (size_t)skk * 1024 + (t) * 64 + sc8);       \
    rv1 = *(const u16x8*)(vtbase + (size_t)(skk + 32) * 1024 + (t) * 64 + sc8);\
} while (0)

#define STORET(bi) do {                                                        \
    *(u16x8*)&Ks[bi][swk][sc8]       = rk0;                                    \
    *(u16x8*)&Ks[bi][swk + 32][sc8]  = rk1;                                    \
    *(u16x8*)&Vts[bi][skk][sc8]      = rv0;                                    \
    *(u16x8*)&Vts[bi][skk + 32][sc8] = rv1;                                    \
} while (0)

#define COMPUTE(bi) do {                                                        \
    _Pragma("unroll")                                                           \
    for (int ks = 0; ks < 2; ++ks) {                                            \
        const int ra = ks * 32 + sra;                                           \
        bf16x8 ka0 = *(const bf16x8*)&Ks[bi][ra][quad * 8];                     \
        bf16x8 ka1 = *(const bf16x8*)&Ks[bi][ra][32 + quad * 8];                \
        bf16x8 kb0 = *(const bf16x8*)&Ks[bi][ra + 8][quad * 8];                 \
        bf16x8 kb1 = *(const bf16x8*)&Ks[bi][ra + 8][32 + quad * 8];            \
        f32x4 za = {}, zb = {};                                                 \
        za = __builtin_amdgcn_mfma_f32_16x16x32_bf16(ka0, aq0, za, 0, 0, 0);    \
        za = __builtin_amdgcn_mfma_f32_16x16x32_bf16(ka1, aq1, za, 0, 0, 0);    \
        zb = __builtin_amdgcn_mfma_f32_16x16x32_bf16(kb0, aq0, zb, 0, 0, 0);    \
        zb = __builtin_amdgcn_mfma_f32_16x16x32_bf16(kb1, aq1, zb, 0, 0, 0);    \
        bf16x8 ap;                                                              \
        _Pragma("unroll")                                                       \
        for (int r = 0; r < 4; ++r) {                                           \
            ap[r]     = (__bf16)exp2f(fminf(za[r], 80.f));                      \
            ap[4 + r] = (__bf16)exp2f(fminf(zb[r], 80.f));                      \
        }                                                                       \
        acc_l = __builtin_amdgcn_mfma_f32_16x16x32_bf16(ap, ones, acc_l, 0, 0, 0);\
        _Pragma("unroll")                                                       \
        for (int nt = 0; nt < 4; ++nt) {                                        \
            bf16x8 bv = *(const bf16x8*)&Vts[bi][nt * 16 + c][ks * 32 + quad * 8];\
            acc_o[nt] = __builtin_amdgcn_mfma_f32_16x16x32_bf16(ap, bv, acc_o[nt], 0, 0, 0);\
        }                                                                       \
    }                                                                           \
} while (0)

    LOADT(0);
    STORET(0);
    for (int t = 0; t < 16; t += 2) {
        __syncthreads();
        LOADT(t + 1);
        COMPUTE(0);
        STORET(1);
        __syncthreads();
        if (t + 2 < 16) LOADT(t + 2);
        COMPUTE(1);
        if (t + 2 < 16) STORET(0);
    }

#undef LOADT
#undef STORET
#undef COMPUTE

#pragma unroll
    for (int nt = 0; nt < 4; ++nt) {
        int col = h * 64 + nt * 16 + c;
#pragma unroll
        for (int r = 0; r < 4; ++r) {
            int row = qrow0 + w * 16 + quad * 4 + r;
            CTX[(size_t)row * 256 + col] = f2bf_fast(acc_o[nt][r] / acc_l[r]);
        }
    }
}

// ---------------- LN2 + logits / KL / flags fused (KL partials) ------------
__global__ __launch_bounds__(256) void k_logits(const u16* __restrict__ FFO,
                                                const u16* __restrict__ Y1,
                                                const u16* __restrict__ g2,
                                                const u16* __restrict__ be2,
                                                const u16* __restrict__ Wl,
                                                const u16* __restrict__ bl,
                                                u16* __restrict__ Y2,
                                                float* __restrict__ klpart,
                                                int* __restrict__ flags) {
    const int tid = threadIdx.x, lane = tid & 63, w = tid >> 6;
    float wv[4][3], gv[4], bev[4];
#pragma unroll
    for (int j = 0; j < 4; ++j) {
        int d = lane * 4 + j;
        gv[j]  = bf2f(g2[d]);
        bev[j] = bf2f(be2[d]);
#pragma unroll
        for (int c = 0; c < 3; ++c) wv[j][c] = bf2f(Wl[d * 3 + c]);
    }
    const float b0 = bf2f(bl[0]), b1 = bf2f(bl[1]), b2 = bf2f(bl[2]);
    float klsum = 0.f;
    const int row0 = blockIdx.x * 16 + w * 4;
    for (int i = 0; i < 4; ++i) {
        int row = row0 + i;
        size_t base = (size_t)row * 256 + lane * 4;
        u16x4 f4 = *(const u16x4*)&FFO[base];
        u16x4 y4 = *(const u16x4*)&Y1[base];
        float v[4];
        float s = 0.f, sq = 0.f;
#pragma unroll
        for (int j = 0; j < 4; ++j) {
            v[j] = bf2f(f4[j]) + bf2f(y4[j]);
            s += v[j]; sq += v[j] * v[j];
        }
        for (int off = 32; off >= 1; off >>= 1) { s += __shfl_xor(s, off); sq += __shfl_xor(sq, off); }
        float mean = s * (1.f / 256.f);
        float var  = sq * (1.f / 256.f) - mean * mean;
        float rs   = rsqrtf(var + 1e-5f);
        u16x4 o;
        float a0 = 0.f, a1 = 0.f, a2 = 0.f;
#pragma unroll
        for (int j = 0; j < 4; ++j) {
            float yn = (v[j] - mean) * rs * gv[j] + bev[j];
            o[j] = f2bf(yn);
            float y = bf2f(o[j]);
            a0 += y * wv[j][0]; a1 += y * wv[j][1]; a2 += y * wv[j][2];
        }
        *(u16x4*)&Y2[base] = o;
        for (int off = 32; off >= 1; off >>= 1) {
            a0 += __shfl_xor(a0, off); a1 += __shfl_xor(a1, off); a2 += __shfl_xor(a2, off);
        }
        if (lane == 0) {
            float l0 = a0 + b0, l1 = a1 + b1, l2 = a2 + b2;
            float mx = fmaxf(l0, fmaxf(l1, l2));
            float lse = mx + __logf(__expf(l0 - mx) + __expf(l1 - mx) + __expf(l2 - mx));
            klsum += lse - (l0 + l1 + l2) * (1.f / 3.f) - 1.0986122886681098f;
            int am = 0; float bv = l0;
            if (l1 > bv) { bv = l1; am = 1; }
            if (l2 > bv) { am = 2; }
            int l = row & 1023;
            flags[row] = (am == 0 && l != 0) ? 1 : 0;
        }
    }
    __shared__ float kls[4];
    if (lane == 0) kls[w] = klsum;
    __syncthreads();
    if (tid == 0) klpart[blockIdx.x] = kls[0] + kls[1] + kls[2] + kls[3];
}

// per-batch exclusive scan: wave shuffle-scan, 2 barriers
__global__ void k_scan(const int* __restrict__ flags, int* __restrict__ seg) {
    __shared__ int wsum[16];
    int b = blockIdx.x, t = threadIdx.x;
    int lane = t & 63, w = t >> 6;
    int f = flags[b * 1024 + t];
    int x = f;
#pragma unroll
    for (int off = 1; off < 64; off <<= 1) {
        int v = __shfl_up(x, off);
        if (lane >= off) x += v;
    }
    if (lane == 63) wsum[w] = x;
    __syncthreads();
    if (w == 0) {
        int s = (lane < 16) ? wsum[lane] : 0;
#pragma unroll
        for (int off = 1; off < 16; off <<= 1) {
            int v = __shfl_up(s, off);
            if (lane >= off) s += v;
        }
        if (lane < 16) wsum[lane] = s;
    }
    __syncthreads();
    int prefix = (w > 0) ? wsum[w - 1] : 0;
    seg[b * 1024 + t] = prefix + x - f;
}

// ---------------- segmean: one block per (b,s); binary-search the run ------
__global__ __launch_bounds__(64) void k_segmean(const u16* __restrict__ Y,
                                                const int* __restrict__ seg,
                                                u16* __restrict__ means,
                                                float* __restrict__ cnt) {
    int g = blockIdx.x, lane = threadIdx.x;
    int b = g >> 10, s = g & 1023;
    const int* sb = seg + b * 1024;
    int target = s + (lane & 1);
    int lo = 0, hi = 1024;
    while (lo < hi) {
        int mid = (lo + hi) >> 1;
        if (sb[mid] < target) lo = mid + 1; else hi = mid;
    }
    int start = __shfl(lo, 0);
    int end   = __shfl(lo, 1);
    int n = end - start;
    if (lane == 0) cnt[g] = (float)n;
    if (n <= 0) return;
    f32x4 acc = {};
    for (int row = start; row < end; ++row) {
        u16x4 y4 = *(const u16x4*)&Y[(size_t)(b * 1024 + row) * 256 + lane * 4];
        acc[0] += bf2f(y4[0]); acc[1] += bf2f(y4[1]);
        acc[2] += bf2f(y4[2]); acc[3] += bf2f(y4[3]);
    }
    float inv = 1.f / (float)n;
    u16x4 o;
#pragma unroll
    for (int j = 0; j < 4; ++j) o[j] = f2bf(acc[j] * inv);
    *(u16x4*)&means[(size_t)g * 256 + lane * 4] = o;
}

// ---------------- finalize: sum KL + pred partials, store ----------------
// predp has 256 entries (16 blocks per batch).
__global__ void k_final(const float* __restrict__ predp, const float* __restrict__ klp,
                        const int* __restrict__ detp, void* __restrict__ outv) {
    int t = threadIdx.x;   // 64
    float k = 0.f;
    for (int i = t; i < 1024; i += 64) k += klp[i];
    for (int off = 32; off >= 1; off >>= 1) k += __shfl_xor(k, off);
    float ktot = __shfl(k, 0);
    int batch = t >> 2, ch = t & 3;
    float c = 0.f, v = 0.f;
    for (int i = 0; i < 4; ++i) {
        int blk = batch * 16 + ch * 4 + i;
        c += predp[2 * blk];
        v += predp[2 * blk + 1];
    }
    c += __shfl_xor(c, 1); c += __shfl_xor(c, 2);
    v += __shfl_xor(v, 1); v += __shfl_xor(v, 2);
    int mode = get_mode(detp);
    if ((t & 3) == 0) {
        float d = v, nm = c;
        if (!(d > 0.f)) d = 1.f;
        if (isnan(nm) || isinf(nm)) nm = 0.f;
        float val = 1.f / (1.f + __expf(-nm / d));
        if (mode) ((float*)outv)[batch] = val;
        else      ((u16*)outv)[batch]   = f2bf(val);
    }
    if (t == 1) {
        float val = ktot * (1.f / 16.f);
        if (isnan(val) || isinf(val)) val = 0.f;
        if (mode) ((float*)outv)[16] = val;
        else      ((u16*)outv)[16]   = f2bf(val);
    }
}

// ---------------------------------------------------------------------------
extern "C" void kernel_launch(void* const* d_in, const int* in_sizes, int n_in,
                              void* d_out, int out_size, void* d_ws, size_t ws_size,
                              hipStream_t stream) {
    const int* shape_idxs = (const int*)d_in[0];
    const int* color_idxs = (const int*)d_in[1];
    char* ws = (char*)d_ws;
    const size_t MB = 1024 * 1024;

    if (ws_size < 90 * MB) {
        int wsMB = (int)(ws_size >> 20); if (wsMB > 250) wsMB = 250;
        k_sentinel_f32<<<1, 32, 0, stream>>>((float*)d_out, 200 + wsMB);
        return;
    }

    // ---- arena ----
    u16*   X     = (u16*)(ws);
    u16*   QKVb  = (u16*)(ws + 8 * MB);
    u16*   VT    = (u16*)(ws + 32 * MB);
    u16*   CTX   = (u16*)(ws + 40 * MB);
    u16*   Y1    = (u16*)(ws + 64 * MB);
    u16*   Hb    = (u16*)(ws);
    u16*   FFO   = (u16*)(ws + 72 * MB);
    u16*   Y2    = (u16*)(ws);
    u16*   MEANS = (u16*)(ws + 24 * MB);
    int*   FLAGS = (int*)(ws + 80 * MB);
    int*   SEG   = (int*)(ws + 80 * MB + 65536);
    float* CNT   = (float*)(ws + 80 * MB + 131072);
    float* KLP   = (float*)(ws + 80 * MB + 262144);
    float* PREDP = (float*)(ws + 80 * MB + 327680);
    u16*   W3T   = (u16*)(ws + 81 * MB);
    u16*   WoT   = (u16*)(ws + 81 * MB + 786432);
    u16*   Wp1T  = (u16*)(ws + 81 * MB + 917504);
    u16*   W1T   = (u16*)(ws + 82 * MB);
    u16*   W2T   = (u16*)(ws + 83 * MB);
    int*   DETP  = (int*)(ws + 84 * MB);
    u16*   ING   = (u16*)(ws + 85 * MB);

    const float QSCALE = 0.125f * 1.44269504f;

    // prep table: 7 transposes + 17 small-tensor ingests + 2048 embed blocks
    PrepTab tt;
    const void* tsrc[7] = {d_in[4], d_in[6], d_in[8], d_in[10], d_in[22], d_in[14], d_in[16]};
    u16* tdst[7] = {W3T, W3T + 256 * 256, W3T + 512 * 256, WoT, Wp1T, W1T, W2T};
    int tK[7] = {256, 256, 256, 256, 256, 256, 2048};
    int tN[7] = {256, 256, 256, 256, 256, 2048, 256};
    int ts = 0;
    for (int i = 0; i < 7; ++i) {
        tt.src[i] = tsrc[i]; tt.dst[i] = tdst[i]; tt.K[i] = tK[i]; tt.N[i] = tN[i];
        tt.scale[i] = (i == 0) ? QSCALE : 1.0f;
        tt.tstart[i] = ts;
        ts += (tK[i] >> 5) * (tN[i] >> 5);
    }
    tt.tstart[7] = ts;

    static const int II[17]  = {5, 7, 9, 11, 12, 13, 15, 17, 18, 19, 20, 21, 23, 24, 25, 26, 27};
    static const int IN[17]  = {256, 256, 256, 256, 256, 256, 2048, 256, 256, 256, 768, 3, 256, 256, 1, 1, 1};
    unsigned off = 0;
    for (int i = 0; i < 17; ++i) {
        tt.isrc[i] = d_in[II[i]];
        tt.in[i] = IN[i];
        tt.iscale[i] = 1.0f;
        if (i == 0) { tt.idstoff[0] = off; off += 768; }
        else if (i == 1) tt.idstoff[1] = tt.idstoff[0] + 256;
        else if (i == 2) tt.idstoff[2] = tt.idstoff[0] + 512;
        else { tt.idstoff[i] = off; off += (unsigned)((IN[i] + 8) & ~7); }
    }
    tt.iscale[0] = QSCALE;   // bq
    tt.ing = ING;
    tt.estart = ts + 17;
    tt.si = shape_idxs; tt.ci = color_idxs;
    tt.se = d_in[2]; tt.ce = d_in[3]; tt.X = X;
    const u16* ib3  = ING + tt.idstoff[0];
    const u16* ibo  = ING + tt.idstoff[3];
    const u16* ig1  = ING + tt.idstoff[4];  const u16* ibe1 = ING + tt.idstoff[5];
    const u16* ibf1 = ING + tt.idstoff[6];  const u16* ibf2 = ING + tt.idstoff[7];
    const u16* ig2  = ING + tt.idstoff[8];  const u16* ibe2 = ING + tt.idstoff[9];
    const u16* iWl  = ING + tt.idstoff[10]; const u16* ibl  = ING + tt.idstoff[11];
    const u16* ibp1 = ING + tt.idstoff[12]; const u16* iWp2 = ING + tt.idstoff[13];
    const u16* ibp2 = ING + tt.idstoff[14]; const u16* iwc  = ING + tt.idstoff[15];
    const u16* ibc  = ING + tt.idstoff[16];

    // 0) detect (plain partials)
    k_detect<<<64, 256, 0, stream>>>((const u16*)d_in[14], DETP);
    // 1) prep: transposes + small ingest + embedding, one launch
    k_prep<<<ts + 17 + 2048, 256, 0, stream>>>(tt, DETP);
    // 2) fused QKV projection; V columns written directly in VT layout
    k_gemm64<<<1536, 256, 0, stream>>>(X, W3T, ib3, QKVb, 768, 256, 0, 6, 32, VT);
    // 3) attention
    k_attn_mfma<<<1024, 256, 0, stream>>>(QKVb, VT, CTX);
    // 4) fused Wo GEMM + residual + LN1 -> Y1
    k_wo_ln<<<1024, 256, 0, stream>>>(CTX, WoT, ibo, X, ig1, ibe1, Y1);
    // 5) FFN1 high-TLP 64x64 (8192 blocks = 32/CU queued), FFN2 64x64
    k_gemm64n<<<8192, 256, 0, stream>>>(Y1, W1T, ibf1, Hb, 2048, 256, 1, 32, 32, nullptr);
    k_gemm64n<<<1024, 256, 0, stream>>>(Hb, W2T, ibf2, FFO, 256, 2048, 0, 4, 32, nullptr);
    // 6) LN2 + logits / KL / flags (fused; writes Y2, KL partials)
    k_logits<<<1024, 256, 0, stream>>>(FFO, Y1, ig2, ibe2, iWl, ibl, Y2, KLP, FLAGS);
    // 7) per-batch exclusive scan
    k_scan<<<16, 1024, 0, stream>>>(FLAGS, SEG);
    // 8) segment means
    k_segmean<<<16384, 64, 0, stream>>>(Y2, SEG, MEANS, CNT);
    // 9) fused predicate head (GEMM + Wp2 dot + sigmoid + partials)
    k_predhead<<<256, 256, 0, stream>>>(MEANS, Wp1T, ibp1, iWp2, ibp2, iwc, ibc, CNT, PREDP);
    // 10) finalize + store
    k_final<<<1, 64, 0, stream>>>(PREDP, KLP, DETP, d_out);
}

// Round 9
// 282.819 us; speedup vs baseline: 1.0578x; 1.0207x over previous
//
#include <hip/hip_runtime.h>

// ---------------------------------------------------------------------------
// B=16, L=1024, D=256, H=4 (DH=64), DFF=2048, C=3. Output: 17 elems.
// Dtype-adaptive (f32 or bf16 inputs; mode from DETP partial sums). Wq/bq
// pre-scaled by 0.125*log2e so attention softmax is bare exp2.
// r26: anchored on r23 (284.8us measured best; r25's FFN1 tile swap was
// within noise -> reverted to k_gemm_bt). Two targeted changes:
// (1) attn exp2f -> __builtin_amdgcn_exp2f (raw v_exp_f32; attn was
//     VALUBusy 54% / MfmaUtil 17%, 256 exp2/thread the largest VALU item;
//     numerics differ only in sub-denormal tail, absorbed by bf16 P cvt).
// (2) k_segmean repacked 4 segments/block (one per wave): 16384 tiny
//     64-thr blocks -> 4096x256; ~95% of segments are empty so the old
//     grid was mostly block-dispatch overhead. Identical per-wave code.
// 12 launches. r23: prep+embed merge, predhead fusion. r22: k_wo_ln.
// r19: attention dbuf K/V + register prefetch. r18: in-register P.
// ---------------------------------------------------------------------------

typedef unsigned short u16;
typedef u16    u16x4  __attribute__((ext_vector_type(4)));
typedef u16    u16x8  __attribute__((ext_vector_type(8)));
typedef __bf16 bf16x8 __attribute__((ext_vector_type(8)));
typedef float  f32x4  __attribute__((ext_vector_type(4)));

__device__ __forceinline__ float bf2f(u16 u) {
    union { unsigned int i; float f; } v; v.i = ((unsigned int)u) << 16; return v.f;
}
__device__ __forceinline__ u16 f2bf(float f) {
    union { float f; unsigned int i; } v; v.f = f;
    unsigned int r = (v.i + 0x7FFFu + ((v.i >> 16) & 1u)) >> 16;
    return (u16)r;
}
__device__ __forceinline__ u16 f2bf_fast(float f) {
    union { __bf16 h; u16 u; } v; v.h = (__bf16)f; return v.u;
}
__device__ __forceinline__ void gll16(const u16* g, u16* l) {
    __builtin_amdgcn_global_load_lds((__attribute__((address_space(1))) void*)(u16*)g,
                                     (__attribute__((address_space(3))) void*)l, 16, 0, 0);
}
__device__ __forceinline__ int get_mode(const int* __restrict__ detp) {
    int s = 0;
#pragma unroll 8
    for (int i = 0; i < 64; ++i) s += detp[i];
    return s > 16;
}

// ---------------- dtype detection: plain per-block partials ----------------
__global__ __launch_bounds__(256) void k_detect(const u16* __restrict__ w1raw,
                                                int* __restrict__ detp) {
    int i = blockIdx.x * 256 + threadIdx.x;
    int bad = 0;
    for (int k = i; k < 65536; k += 64 * 256) {
        unsigned v = w1raw[k] & 0x7FFFu;
        if (v >= 0x7F80u) bad++;
    }
    for (int off = 32; off >= 1; off >>= 1) bad += __shfl_xor(bad, off);
    __shared__ int bs[4];
    if ((threadIdx.x & 63) == 0) bs[threadIdx.x >> 6] = bad;
    __syncthreads();
    if (threadIdx.x == 0) detp[blockIdx.x] = bs[0] + bs[1] + bs[2] + bs[3];
}
__global__ void k_sentinel_f32(float* __restrict__ out, int code) {
    int t = threadIdx.x;
    if (t < 17) out[t] = (float)code;
}

// ------- prep: transposes + small ingest + embedding, one launch -----------
struct PrepTab {
    const void* src[7];
    u16*        dst[7];
    int         K[7], N[7];
    float       scale[7];
    int         tstart[8];     // transpose tile ranges; ingest = [tstart[7], +17)
    const void* isrc[17];
    unsigned    idstoff[17];
    int         in[17];
    float       iscale[17];
    u16*        ing;
    int         estart;        // embed blocks start here
    const int*  si;
    const int*  ci;
    const void* se;
    const void* ce;
    u16*        X;
};
__global__ __launch_bounds__(256) void k_prep(PrepTab tt, const int* __restrict__ detp) {
    int m = get_mode(detp);
    int bx = blockIdx.x;
    if (bx >= tt.estart) {                    // ---- embedding ----
        int t = (bx - tt.estart) * 256 + threadIdx.x;
        int row = t >> 5, seg = (t & 31) * 8;
        int s = tt.si[row], c = tt.ci[row];
        u16x8 o;
        if (m) {
            const float* sp = (const float*)tt.se + s * 256 + seg;
            const float* cp = (const float*)tt.ce + c * 256 + seg;
#pragma unroll
            for (int e = 0; e < 8; ++e) o[e] = f2bf(sp[e] + cp[e]);
        } else {
            u16x8 a = *(const u16x8*)((const u16*)tt.se + s * 256 + seg);
            u16x8 b = *(const u16x8*)((const u16*)tt.ce + c * 256 + seg);
#pragma unroll
            for (int e = 0; e < 8; ++e) o[e] = f2bf(bf2f(a[e]) + bf2f(b[e]));
        }
        *(u16x8*)&tt.X[(size_t)row * 256 + seg] = o;
        return;
    }
    if (bx >= tt.tstart[7]) {                 // ---- small-tensor ingest ----
        int t = bx - tt.tstart[7];
        int n = tt.in[t];
        float sc = tt.iscale[t];
        u16* dst = tt.ing + tt.idstoff[t];
        for (int i = threadIdx.x; i < n; i += 256) {
            float v = m ? ((const float*)tt.isrc[t])[i] : bf2f(((const u16*)tt.isrc[t])[i]);
            dst[i] = f2bf(v * sc);
        }
        return;
    }
    __shared__ u16 tile[32][33];
    int wgt = 0;
#pragma unroll
    for (int i = 1; i < 7; ++i) if (bx >= tt.tstart[i]) wgt = i;
    int local = bx - tt.tstart[wgt];
    int K = tt.K[wgt], N = tt.N[wgt];
    float sc = tt.scale[wgt];
    int ntx = N >> 5;
    int txt = local % ntx, tyt = local / ntx;
    const void* W = tt.src[wgt];
    u16* Wt = tt.dst[wgt];
    int tx = threadIdx.x & 31, ty = threadIdx.x >> 5;
    int n = txt * 32 + tx;
    for (int i = ty; i < 32; i += 8) {
        size_t idx = (size_t)(tyt * 32 + i) * N + n;
        float v = m ? ((const float*)W)[idx] : bf2f(((const u16*)W)[idx]);
        tile[i][tx] = f2bf(v * sc);
    }
    __syncthreads();
    int k2 = tyt * 32 + tx;
    for (int i = ty; i < 32; i += 8) {
        int n2 = txt * 32 + i;
        Wt[(size_t)n2 * K + k2] = tile[tx][i];
    }
}

// ---------------- MFMA GEMM 128x128, gll16, XCD-banded (FFN1) --------------
// r19 structure (measured best): BK=32, single buffer, 4-load burst + drain.
__global__ __launch_bounds__(256) void k_gemm_bt(const u16* __restrict__ A,
                                                 const u16* __restrict__ Bt,
                                                 const u16* __restrict__ bias,
                                                 u16* __restrict__ C,
                                                 int N, int K, int relu, int gx) {
    __shared__ u16 As[128][32];
    __shared__ u16 Bs[128][32];
    const int tid = threadIdx.x;
    const int xcd = blockIdx.x & 7, j = blockIdx.x >> 3;
    const int m0 = (xcd * 16 + j / gx) * 128, n0 = (j % gx) * 128;
    const int lane = tid & 63, wid = tid >> 6;
    const int wm = (wid & 1) * 64, wn = (wid >> 1) * 64;
    const int m16 = lane & 15, quad = lane >> 4;
    f32x4 acc[4][4] = {};
    const int arow = tid >> 2;
    const int ac8  = (tid & 3) * 8;
    const u16* Ap0 = A  + (size_t)(m0 + arow) * K + ac8;
    const u16* Ap1 = A  + (size_t)(m0 + 64 + arow) * K + ac8;
    const u16* Bp0 = Bt + (size_t)(n0 + arow) * K + ac8;
    const u16* Bp1 = Bt + (size_t)(n0 + 64 + arow) * K + ac8;
    u16* lA0 = &As[arow][ac8];
    u16* lA1 = &As[64 + arow][ac8];
    u16* lB0 = &Bs[arow][ac8];
    u16* lB1 = &Bs[64 + arow][ac8];

    for (int k0 = 0; k0 < K; k0 += 32) {
        __syncthreads();
        gll16(Ap0 + k0, lA0);
        gll16(Ap1 + k0, lA1);
        gll16(Bp0 + k0, lB0);
        gll16(Bp1 + k0, lB1);
        __syncthreads();
        bf16x8 af[4], bfv[4];
#pragma unroll
        for (int i = 0; i < 4; ++i)
            af[i] = *(const bf16x8*)&As[wm + i * 16 + m16][quad * 8];
#pragma unroll
        for (int j2 = 0; j2 < 4; ++j2)
            bfv[j2] = *(const bf16x8*)&Bs[wn + j2 * 16 + m16][quad * 8];
#pragma unroll
        for (int i = 0; i < 4; ++i)
#pragma unroll
            for (int j2 = 0; j2 < 4; ++j2)
                acc[i][j2] = __builtin_amdgcn_mfma_f32_16x16x32_bf16(
                    af[i], bfv[j2], acc[i][j2], 0, 0, 0);
    }

#pragma unroll
    for (int i = 0; i < 4; ++i) {
        int row = m0 + wm + i * 16 + quad * 4;
#pragma unroll
        for (int j2 = 0; j2 < 4; ++j2) {
            int col = n0 + wn + j2 * 16 + m16;
            float bv = bf2f(bias[col]);
#pragma unroll
            for (int r = 0; r < 4; ++r) {
                float v = acc[i][j2][r] + bv;
                if (relu) v = fmaxf(v, 0.f);
                C[(size_t)(row + r) * N + col] = f2bf_fast(v);
            }
        }
    }
}

// ---------------- MFMA GEMM 64x128, BK=64 (QKV; vt epilogue) ---------------
__global__ __launch_bounds__(256) void k_gemm64(const u16* __restrict__ A,
                                                const u16* __restrict__ Bt,
                                                const u16* __restrict__ bias,
                                                u16* __restrict__ C,
                                                int N, int K, int relu,
                                                int gx, int mtpx,
                                                u16* __restrict__ vt) {
    __shared__ u16 As0[64][32], As1[64][32];
    __shared__ u16 Bs0[128][32], Bs1[128][32];
    const int tid = threadIdx.x;
    const int xcd = blockIdx.x & 7, j = blockIdx.x >> 3;
    const int m0 = (xcd * mtpx + j / gx) * 64, n0 = (j % gx) * 128;
    const int vmode = (vt != nullptr) && (n0 >= 512);
    const int lane = tid & 63, wid = tid >> 6;
    const int wm = (wid & 1) * 32, wn = (wid >> 1) * 64;
    const int m16 = lane & 15, quad = lane >> 4;
    f32x4 acc[2][4] = {};
    const int arow = tid >> 2;
    const int ac8  = (tid & 3) * 8;
    const u16* Ap  = A  + (size_t)(m0 + arow) * K + ac8;
    const u16* Bp0 = Bt + (size_t)(n0 + arow) * K + ac8;
    const u16* Bp1 = Bt + (size_t)(n0 + 64 + arow) * K + ac8;
    u16* lA0  = &As0[arow][ac8];
    u16* lA1  = &As1[arow][ac8];
    u16* lB00 = &Bs0[arow][ac8];
    u16* lB01 = &Bs0[64 + arow][ac8];
    u16* lB10 = &Bs1[arow][ac8];
    u16* lB11 = &Bs1[64 + arow][ac8];

    for (int k0 = 0; k0 < K; k0 += 64) {
        __syncthreads();
        gll16(Ap + k0,        lA0);
        gll16(Ap + k0 + 32,   lA1);
        gll16(Bp0 + k0,       lB00);
        gll16(Bp0 + k0 + 32,  lB10);
        gll16(Bp1 + k0,       lB01);
        gll16(Bp1 + k0 + 32,  lB11);
        __syncthreads();
#pragma unroll
        for (int ks = 0; ks < 2; ++ks) {
            bf16x8 af[2], bfv[4];
#pragma unroll
            for (int i = 0; i < 2; ++i)
                af[i] = ks == 0 ? *(const bf16x8*)&As0[wm + i * 16 + m16][quad * 8]
                                : *(const bf16x8*)&As1[wm + i * 16 + m16][quad * 8];
#pragma unroll
            for (int j2 = 0; j2 < 4; ++j2)
                bfv[j2] = ks == 0 ? *(const bf16x8*)&Bs0[wn + j2 * 16 + m16][quad * 8]
                                  : *(const bf16x8*)&Bs1[wn + j2 * 16 + m16][quad * 8];
#pragma unroll
            for (int i = 0; i < 2; ++i)
#pragma unroll
                for (int j2 = 0; j2 < 4; ++j2)
                    acc[i][j2] = __builtin_amdgcn_mfma_f32_16x16x32_bf16(
                        af[i], bfv[j2], acc[i][j2], 0, 0, 0);
        }
    }

#pragma unroll
    for (int i = 0; i < 2; ++i) {
        int row = m0 + wm + i * 16 + quad * 4;
#pragma unroll
        for (int j2 = 0; j2 < 4; ++j2) {
            int col = n0 + wn + j2 * 16 + m16;
            float bv = bf2f(bias[col]);
            if (vmode) {
                int ch = col - 512;
                u16x4 o;
#pragma unroll
                for (int r = 0; r < 4; ++r) o[r] = f2bf_fast(acc[i][j2][r] + bv);
                size_t vb = ((size_t)((row >> 10) * 4 + (ch >> 6)) * 64 + (ch & 63)) * 1024
                          + (row & 1023);
                *(u16x4*)&vt[vb] = o;
            } else {
#pragma unroll
                for (int r = 0; r < 4; ++r) {
                    float v = acc[i][j2][r] + bv;
                    if (relu) v = fmaxf(v, 0.f);
                    C[(size_t)(row + r) * N + col] = f2bf_fast(v);
                }
            }
        }
    }
}

// ---------------- MFMA GEMM 64x64, BK=64 — high-TLP (FFN2) -----------------
__global__ __launch_bounds__(256) void k_gemm64n(const u16* __restrict__ A,
                                                 const u16* __restrict__ Bt,
                                                 const u16* __restrict__ bias,
                                                 u16* __restrict__ C,
                                                 int N, int K, int relu,
                                                 int gnx, int mtpx,
                                                 const float* __restrict__ gate) {
    __shared__ u16 As0[64][32], As1[64][32];
    __shared__ u16 Bs0[64][32], Bs1[64][32];
    const int tid = threadIdx.x;
    const int xcd = blockIdx.x & 7, j = blockIdx.x >> 3;
    const int m0 = (xcd * mtpx + j / gnx) * 64, n0 = (j % gnx) * 64;
    if (gate && gate[m0] == 0.f) return;
    const int lane = tid & 63, w = tid >> 6;
    const int m16 = lane & 15, quad = lane >> 4;
    f32x4 acc[4] = {};
    const int arow = tid >> 2;          // 0..63
    const int ac8  = (tid & 3) * 8;     // 0,8,16,24
    const u16* Ap = A  + (size_t)(m0 + arow) * K + ac8;
    const u16* Bp = Bt + (size_t)(n0 + arow) * K + ac8;
    u16* lA0 = &As0[arow][ac8];
    u16* lA1 = &As1[arow][ac8];
    u16* lB0 = &Bs0[arow][ac8];
    u16* lB1 = &Bs1[arow][ac8];

    for (int k0 = 0; k0 < K; k0 += 64) {
        __syncthreads();
        gll16(Ap + k0,       lA0);
        gll16(Ap + k0 + 32,  lA1);
        gll16(Bp + k0,       lB0);
        gll16(Bp + k0 + 32,  lB1);
        __syncthreads();
#pragma unroll
        for (int ks = 0; ks < 2; ++ks) {
            bf16x8 af = ks == 0 ? *(const bf16x8*)&As0[w * 16 + m16][quad * 8]
                                : *(const bf16x8*)&As1[w * 16 + m16][quad * 8];
#pragma unroll
            for (int nt = 0; nt < 4; ++nt) {
                bf16x8 bfv = ks == 0 ? *(const bf16x8*)&Bs0[nt * 16 + m16][quad * 8]
                                     : *(const bf16x8*)&Bs1[nt * 16 + m16][quad * 8];
                acc[nt] = __builtin_amdgcn_mfma_f32_16x16x32_bf16(af, bfv, acc[nt], 0, 0, 0);
            }
        }
    }

#pragma unroll
    for (int nt = 0; nt < 4; ++nt) {
        int col = n0 + nt * 16 + m16;
        float bv = bf2f(bias[col]);
        int row = m0 + w * 16 + quad * 4;
#pragma unroll
        for (int r = 0; r < 4; ++r) {
            float v = acc[nt][r] + bv;
            if (relu) v = fmaxf(v, 0.f);
            C[(size_t)(row + r) * N + col] = f2bf_fast(v);
        }
    }
}

// ---------------------------------------------------------------------------
// r22: fused Wo-GEMM + residual + LayerNorm1 (validated). 16x256 tile/block.
// ---------------------------------------------------------------------------
__global__ __launch_bounds__(256) void k_wo_ln(const u16* __restrict__ A,
                                               const u16* __restrict__ Bt,
                                               const u16* __restrict__ bias,
                                               const u16* __restrict__ X,
                                               const u16* __restrict__ g,
                                               const u16* __restrict__ be,
                                               u16* __restrict__ Y1) {
    __shared__ u16 As0[16][32], As1[16][32];
    __shared__ u16 Bs0[256][32], Bs1[256][32];
    __shared__ float lnp[2][4][16];
    const int tid = threadIdx.x, lane = tid & 63, w = tid >> 6;
    const int m16 = lane & 15, quad = lane >> 4;
    const int xcd = blockIdx.x & 7, j = blockIdx.x >> 3;
    const int m0 = (xcd * 128 + j) * 16;
    const int K = 256;
    f32x4 acc[4] = {};
    const int an = lane >> 2, ac = (lane & 3) * 8;

    for (int k0 = 0; k0 < K; k0 += 64) {
        __syncthreads();
#pragma unroll
        for (int i = 0; i < 4; ++i) {
            int ch = i * 256 + tid;
            int n = ch >> 2, kc = (ch & 3) * 8;
            gll16(Bt + (size_t)n * K + k0 + kc,      &Bs0[n][kc]);
            gll16(Bt + (size_t)n * K + k0 + 32 + kc, &Bs1[n][kc]);
        }
        if (w == 0) gll16(A + (size_t)(m0 + an) * K + k0 + ac,      &As0[an][ac]);
        if (w == 1) gll16(A + (size_t)(m0 + an) * K + k0 + 32 + ac, &As1[an][ac]);
        __syncthreads();
#pragma unroll
        for (int ks = 0; ks < 2; ++ks) {
            bf16x8 af = ks == 0 ? *(const bf16x8*)&As0[m16][quad * 8]
                                : *(const bf16x8*)&As1[m16][quad * 8];
#pragma unroll
            for (int nt = 0; nt < 4; ++nt) {
                bf16x8 bfv = ks == 0
                    ? *(const bf16x8*)&Bs0[w * 64 + nt * 16 + m16][quad * 8]
                    : *(const bf16x8*)&Bs1[w * 64 + nt * 16 + m16][quad * 8];
                acc[nt] = __builtin_amdgcn_mfma_f32_16x16x32_bf16(af, bfv, acc[nt], 0, 0, 0);
            }
        }
    }

    float vln[4][4];
    float s[4] = {0.f, 0.f, 0.f, 0.f}, sq[4] = {0.f, 0.f, 0.f, 0.f};
#pragma unroll
    for (int nt = 0; nt < 4; ++nt) {
        int col = w * 64 + nt * 16 + m16;
        float bv = bf2f(bias[col]);
#pragma unroll
        for (int r = 0; r < 4; ++r) {
            int row = m0 + quad * 4 + r;
            u16 c16 = f2bf_fast(acc[nt][r] + bv);
            float v = bf2f(c16) + bf2f(X[(size_t)row * 256 + col]);
            vln[nt][r] = v;
            s[r] += v; sq[r] += v * v;
        }
    }
#pragma unroll
    for (int r = 0; r < 4; ++r)
        for (int off = 1; off < 16; off <<= 1) {
            s[r]  += __shfl_xor(s[r], off);
            sq[r] += __shfl_xor(sq[r], off);
        }
    if (m16 == 0) {
#pragma unroll
        for (int r = 0; r < 4; ++r) {
            lnp[0][w][quad * 4 + r] = s[r];
            lnp[1][w][quad * 4 + r] = sq[r];
        }
    }
    __syncthreads();
#pragma unroll
    for (int r = 0; r < 4; ++r) {
        int rw = quad * 4 + r;
        float st  = lnp[0][0][rw] + lnp[0][1][rw] + lnp[0][2][rw] + lnp[0][3][rw];
        float sqt = lnp[1][0][rw] + lnp[1][1][rw] + lnp[1][2][rw] + lnp[1][3][rw];
        float mean = st * (1.f / 256.f);
        float var  = sqt * (1.f / 256.f) - mean * mean;
        float rs   = rsqrtf(var + 1e-5f);
        int row = m0 + rw;
#pragma unroll
        for (int nt = 0; nt < 4; ++nt) {
            int col = w * 64 + nt * 16 + m16;
            Y1[(size_t)row * 256 + col] =
                f2bf((vln[nt][r] - mean) * rs * bf2f(g[col]) + bf2f(be[col]));
        }
    }
}

// ---------------------------------------------------------------------------
// r23: fused predicate head — 64x256-tile GEMM (relu(means@Wp1+bp1)) with
// in-block Wp2 dot + sigmoid + per-block comp partials.
// ---------------------------------------------------------------------------
__global__ __launch_bounds__(256) void k_predhead(const u16* __restrict__ A,
                                                  const u16* __restrict__ Bt,
                                                  const u16* __restrict__ bp1,
                                                  const u16* __restrict__ Wp2,
                                                  const u16* __restrict__ bp2,
                                                  const u16* __restrict__ wc,
                                                  const u16* __restrict__ bc,
                                                  const float* __restrict__ cnt,
                                                  float* __restrict__ predp) {
    const int tid = threadIdx.x;
    const int m0 = blockIdx.x * 64;
    if (cnt[m0] == 0.f) {
        if (tid == 0) { predp[2 * blockIdx.x] = 0.f; predp[2 * blockIdx.x + 1] = 0.f; }
        return;
    }
    __shared__ u16 As0[64][32], As1[64][32];
    __shared__ u16 Bs0[256][32], Bs1[256][32];
    __shared__ float cs[4], vs[4];
    const int lane = tid & 63, w = tid >> 6;
    const int m16 = lane & 15, quad = lane >> 4;
    f32x4 acc[16] = {};
    const int ar = tid >> 2, akc = (tid & 3) * 8;

    for (int k0 = 0; k0 < 256; k0 += 64) {
        __syncthreads();
        gll16(A + (size_t)(m0 + ar) * 256 + k0 + akc,      &As0[ar][akc]);
        gll16(A + (size_t)(m0 + ar) * 256 + k0 + 32 + akc, &As1[ar][akc]);
#pragma unroll
        for (int i = 0; i < 4; ++i) {
            int ch = i * 256 + tid;
            int n = ch >> 2, kc = (ch & 3) * 8;
            gll16(Bt + (size_t)n * 256 + k0 + kc,      &Bs0[n][kc]);
            gll16(Bt + (size_t)n * 256 + k0 + 32 + kc, &Bs1[n][kc]);
        }
        __syncthreads();
#pragma unroll
        for (int ks = 0; ks < 2; ++ks) {
            bf16x8 af = ks == 0 ? *(const bf16x8*)&As0[w * 16 + m16][quad * 8]
                                : *(const bf16x8*)&As1[w * 16 + m16][quad * 8];
#pragma unroll
            for (int nt = 0; nt < 16; ++nt) {
                bf16x8 bfv = ks == 0 ? *(const bf16x8*)&Bs0[nt * 16 + m16][quad * 8]
                                     : *(const bf16x8*)&Bs1[nt * 16 + m16][quad * 8];
                acc[nt] = __builtin_amdgcn_mfma_f32_16x16x32_bf16(af, bfv, acc[nt], 0, 0, 0);
            }
        }
    }

    const float fb = bf2f(bp2[0]), fw = bf2f(wc[0]), fc = bf2f(bc[0]);
    float part[4] = {0.f, 0.f, 0.f, 0.f};
#pragma unroll
    for (int nt = 0; nt < 16; ++nt) {
        int col = nt * 16 + m16;
        float bv = bf2f(bp1[col]);
        float wp = bf2f(Wp2[col]);
#pragma unroll
        for (int r = 0; r < 4; ++r) {
            float t = fmaxf(acc[nt][r] + bv, 0.f);
            part[r] += bf2f(f2bf_fast(t)) * wp;   // replicate TB bf16 round-trip
        }
    }
#pragma unroll
    for (int r = 0; r < 4; ++r)
        for (int off = 1; off < 16; off <<= 1)
            part[r] += __shfl_xor(part[r], off);

    float csum = 0.f, vsum = 0.f;
    if (m16 == 0) {
#pragma unroll
        for (int r = 0; r < 4; ++r) {
            int row = m0 + w * 16 + quad * 4 + r;
            if (cnt[row] > 0.f) {
                float pred = 1.f / (1.f + __expf(-(part[r] + fb)));
                csum += pred * fw + fc;
                vsum += 1.f;
            }
        }
    }
    csum += __shfl_xor(csum, 16); csum += __shfl_xor(csum, 32);
    vsum += __shfl_xor(vsum, 16); vsum += __shfl_xor(vsum, 32);
    if (lane == 0) { cs[w] = csum; vs[w] = vsum; }
    __syncthreads();
    if (tid == 0) {
        predp[2 * blockIdx.x]     = cs[0] + cs[1] + cs[2] + cs[3];
        predp[2 * blockIdx.x + 1] = vs[0] + vs[1] + vs[2] + vs[3];
    }
}

// ---------------------------------------------------------------------------
// MFMA flash attention — r19 structure; r26: raw v_exp_f32 via
// __builtin_amdgcn_exp2f (attn was VALU-bound: 54% VALUBusy vs 17% MfmaUtil).
// In-register P via swapped QK^T (mfma(K,Q)) + key-slot permutation; K
// stored at bit2<->bit3-swapped rows. 36.9KB LDS, 4 blocks/CU, 1024 blocks.
// ---------------------------------------------------------------------------
__global__ __launch_bounds__(256) void k_attn_mfma(const u16* __restrict__ QKV,
                                                   const u16* __restrict__ VT,
                                                   u16* __restrict__ CTX) {
    __shared__ u16 Ks[2][64][72];
    __shared__ u16 Vts[2][64][72];
    const int tid = threadIdx.x, lane = tid & 63, w = tid >> 6;
    const int quad = lane >> 4, c = lane & 15;
    const int blk = blockIdx.x;
    const int xcd = blk & 7, local = blk >> 3;
    const int bh = xcd * 8 + (local >> 4);
    const int qt = local & 15;
    const int b = bh >> 2, h = bh & 3;
    const int qrow0 = b * 1024 + qt * 64;

    const u16* qptr = QKV + (size_t)(qrow0 + w * 16 + c) * 768 + h * 64;
    bf16x8 aq0 = *(const bf16x8*)(qptr + quad * 8);
    bf16x8 aq1 = *(const bf16x8*)(qptr + 32 + quad * 8);

    bf16x8 ones;
    {
        union { u16 u; __bf16 h; } v; v.u = 0x3F80;
#pragma unroll
        for (int e = 0; e < 8; ++e) ones[e] = v.h;
    }

    f32x4 acc_o[4] = {};
    f32x4 acc_l = {};

    const u16* kbase  = QKV + (size_t)(b * 1024) * 768 + 256 + h * 64;
    const u16* vtbase = VT + (size_t)(bh * 64) * 1024;
    const int skk = tid >> 3, sc8 = (tid & 7) * 8;
    const int swk = (skk & ~12) | ((skk & 4) << 1) | ((skk & 8) >> 1);
    const int sra = ((c & 8) << 1) | (c & 4) | (c & 3);

    u16x8 rk0, rk1, rv0, rv1;

#define LOADT(t) do {                                                          \
    rk0 = *(const u16x8*)(kbase + (size_t)((t) * 64 + skk) * 768 + sc8);       \
    rk1 = *(const u16x8*)(kbase + (size_t)((t) * 64 + skk + 32) * 768 + sc8);  \
    rv0 = *(const u16x8*)(vtbase + (size_t)skk * 1024 + (t) * 64 + sc8);       \
    rv1 = *(const u16x8*)(vtbase + (size_t)(skk + 32) * 1024 + (t) * 64 + sc8);\
} while (0)

#define STORET(bi) do {                                                        \
    *(u16x8*)&Ks[bi][swk][sc8]       = rk0;                                    \
    *(u16x8*)&Ks[bi][swk + 32][sc8]  = rk1;                                    \
    *(u16x8*)&Vts[bi][skk][sc8]      = rv0;                                    \
    *(u16x8*)&Vts[bi][skk + 32][sc8] = rv1;                                    \
} while (0)

#define COMPUTE(bi) do {                                                        \
    _Pragma("unroll")                                                           \
    for (int ks = 0; ks < 2; ++ks) {                                            \
        const int ra = ks * 32 + sra;                                           \
        bf16x8 ka0 = *(const bf16x8*)&Ks[bi][ra][quad * 8];                     \
        bf16x8 ka1 = *(const bf16x8*)&Ks[bi][ra][32 + quad * 8];                \
        bf16x8 kb0 = *(const bf16x8*)&Ks[bi][ra + 8][quad * 8];                 \
        bf16x8 kb1 = *(const bf16x8*)&Ks[bi][ra + 8][32 + quad * 8];            \
        f32x4 za = {}, zb = {};                                                 \
        za = __builtin_amdgcn_mfma_f32_16x16x32_bf16(ka0, aq0, za, 0, 0, 0);    \
        za = __builtin_amdgcn_mfma_f32_16x16x32_bf16(ka1, aq1, za, 0, 0, 0);    \
        zb = __builtin_amdgcn_mfma_f32_16x16x32_bf16(kb0, aq0, zb, 0, 0, 0);    \
        zb = __builtin_amdgcn_mfma_f32_16x16x32_bf16(kb1, aq1, zb, 0, 0, 0);    \
        bf16x8 ap;                                                              \
        _Pragma("unroll")                                                       \
        for (int r = 0; r < 4; ++r) {                                           \
            ap[r]     = (__bf16)__builtin_amdgcn_exp2f(fminf(za[r], 80.f));     \
            ap[4 + r] = (__bf16)__builtin_amdgcn_exp2f(fminf(zb[r], 80.f));     \
        }                                                                       \
        acc_l = __builtin_amdgcn_mfma_f32_16x16x32_bf16(ap, ones, acc_l, 0, 0, 0);\
        _Pragma("unroll")                                                       \
        for (int nt = 0; nt < 4; ++nt) {                                        \
            bf16x8 bv = *(const bf16x8*)&Vts[bi][nt * 16 + c][ks * 32 + quad * 8];\
            acc_o[nt] = __builtin_amdgcn_mfma_f32_16x16x32_bf16(ap, bv, acc_o[nt], 0, 0, 0);\
        }                                                                       \
    }                                                                           \
} while (0)

    LOADT(0);
    STORET(0);
    for (int t = 0; t < 16; t += 2) {
        __syncthreads();
        LOADT(t + 1);
        COMPUTE(0);
        STORET(1);
        __syncthreads();
        if (t + 2 < 16) LOADT(t + 2);
        COMPUTE(1);
        if (t + 2 < 16) STORET(0);
    }

#undef LOADT
#undef STORET
#undef COMPUTE

#pragma unroll
    for (int nt = 0; nt < 4; ++nt) {
        int col = h * 64 + nt * 16 + c;
#pragma unroll
        for (int r = 0; r < 4; ++r) {
            int row = qrow0 + w * 16 + quad * 4 + r;
            CTX[(size_t)row * 256 + col] = f2bf_fast(acc_o[nt][r] / acc_l[r]);
        }
    }
}

// ---------------- LN2 + logits / KL / flags fused (KL partials) ------------
__global__ __launch_bounds__(256) void k_logits(const u16* __restrict__ FFO,
                                                const u16* __restrict__ Y1,
                                                const u16* __restrict__ g2,
                                                const u16* __restrict__ be2,
                                                const u16* __restrict__ Wl,
                                                const u16* __restrict__ bl,
                                                u16* __restrict__ Y2,
                                                float* __restrict__ klpart,
                                                int* __restrict__ flags) {
    const int tid = threadIdx.x, lane = tid & 63, w = tid >> 6;
    float wv[4][3], gv[4], bev[4];
#pragma unroll
    for (int j = 0; j < 4; ++j) {
        int d = lane * 4 + j;
        gv[j]  = bf2f(g2[d]);
        bev[j] = bf2f(be2[d]);
#pragma unroll
        for (int c = 0; c < 3; ++c) wv[j][c] = bf2f(Wl[d * 3 + c]);
    }
    const float b0 = bf2f(bl[0]), b1 = bf2f(bl[1]), b2 = bf2f(bl[2]);
    float klsum = 0.f;
    const int row0 = blockIdx.x * 16 + w * 4;
    for (int i = 0; i < 4; ++i) {
        int row = row0 + i;
        size_t base = (size_t)row * 256 + lane * 4;
        u16x4 f4 = *(const u16x4*)&FFO[base];
        u16x4 y4 = *(const u16x4*)&Y1[base];
        float v[4];
        float s = 0.f, sq = 0.f;
#pragma unroll
        for (int j = 0; j < 4; ++j) {
            v[j] = bf2f(f4[j]) + bf2f(y4[j]);
            s += v[j]; sq += v[j] * v[j];
        }
        for (int off = 32; off >= 1; off >>= 1) { s += __shfl_xor(s, off); sq += __shfl_xor(sq, off); }
        float mean = s * (1.f / 256.f);
        float var  = sq * (1.f / 256.f) - mean * mean;
        float rs   = rsqrtf(var + 1e-5f);
        u16x4 o;
        float a0 = 0.f, a1 = 0.f, a2 = 0.f;
#pragma unroll
        for (int j = 0; j < 4; ++j) {
            float yn = (v[j] - mean) * rs * gv[j] + bev[j];
            o[j] = f2bf(yn);
            float y = bf2f(o[j]);
            a0 += y * wv[j][0]; a1 += y * wv[j][1]; a2 += y * wv[j][2];
        }
        *(u16x4*)&Y2[base] = o;
        for (int off = 32; off >= 1; off >>= 1) {
            a0 += __shfl_xor(a0, off); a1 += __shfl_xor(a1, off); a2 += __shfl_xor(a2, off);
        }
        if (lane == 0) {
            float l0 = a0 + b0, l1 = a1 + b1, l2 = a2 + b2;
            float mx = fmaxf(l0, fmaxf(l1, l2));
            float lse = mx + __logf(__expf(l0 - mx) + __expf(l1 - mx) + __expf(l2 - mx));
            klsum += lse - (l0 + l1 + l2) * (1.f / 3.f) - 1.0986122886681098f;
            int am = 0; float bv = l0;
            if (l1 > bv) { bv = l1; am = 1; }
            if (l2 > bv) { am = 2; }
            int l = row & 1023;
            flags[row] = (am == 0 && l != 0) ? 1 : 0;
        }
    }
    __shared__ float kls[4];
    if (lane == 0) kls[w] = klsum;
    __syncthreads();
    if (tid == 0) klpart[blockIdx.x] = kls[0] + kls[1] + kls[2] + kls[3];
}

// per-batch exclusive scan: wave shuffle-scan, 2 barriers
__global__ void k_scan(const int* __restrict__ flags, int* __restrict__ seg) {
    __shared__ int wsum[16];
    int b = blockIdx.x, t = threadIdx.x;
    int lane = t & 63, w = t >> 6;
    int f = flags[b * 1024 + t];
    int x = f;
#pragma unroll
    for (int off = 1; off < 64; off <<= 1) {
        int v = __shfl_up(x, off);
        if (lane >= off) x += v;
    }
    if (lane == 63) wsum[w] = x;
    __syncthreads();
    if (w == 0) {
        int s = (lane < 16) ? wsum[lane] : 0;
#pragma unroll
        for (int off = 1; off < 16; off <<= 1) {
            int v = __shfl_up(s, off);
            if (lane >= off) s += v;
        }
        if (lane < 16) wsum[lane] = s;
    }
    __syncthreads();
    int prefix = (w > 0) ? wsum[w - 1] : 0;
    seg[b * 1024 + t] = prefix + x - f;
}

// ---------------- segmean: 4 segments per block (one per wave) -------------
// r26: 16384 tiny 64-thr blocks -> 4096x256 (same per-wave algorithm);
// ~95% of segments are empty, old grid was mostly dispatch overhead.
__global__ __launch_bounds__(256) void k_segmean(const u16* __restrict__ Y,
                                                 const int* __restrict__ seg,
                                                 u16* __restrict__ means,
                                                 float* __restrict__ cnt) {
    int wv = threadIdx.x >> 6, lane = threadIdx.x & 63;
    int g = blockIdx.x * 4 + wv;
    int b = g >> 10, s = g & 1023;
    const int* sb = seg + b * 1024;
    int target = s + (lane & 1);
    int lo = 0, hi = 1024;
    while (lo < hi) {
        int mid = (lo + hi) >> 1;
        if (sb[mid] < target) lo = mid + 1; else hi = mid;
    }
    int start = __shfl(lo, 0);
    int end   = __shfl(lo, 1);
    int n = end - start;
    if (lane == 0) cnt[g] = (float)n;
    if (n <= 0) return;
    f32x4 acc = {};
    for (int row = start; row < end; ++row) {
        u16x4 y4 = *(const u16x4*)&Y[(size_t)(b * 1024 + row) * 256 + lane * 4];
        acc[0] += bf2f(y4[0]); acc[1] += bf2f(y4[1]);
        acc[2] += bf2f(y4[2]); acc[3] += bf2f(y4[3]);
    }
    float inv = 1.f / (float)n;
    u16x4 o;
#pragma unroll
    for (int j = 0; j < 4; ++j) o[j] = f2bf(acc[j] * inv);
    *(u16x4*)&means[(size_t)g * 256 + lane * 4] = o;
}

// ---------------- finalize: sum KL + pred partials, store ----------------
// predp has 256 entries (16 blocks per batch).
__global__ void k_final(const float* __restrict__ predp, const float* __restrict__ klp,
                        const int* __restrict__ detp, void* __restrict__ outv) {
    int t = threadIdx.x;   // 64
    float k = 0.f;
    for (int i = t; i < 1024; i += 64) k += klp[i];
    for (int off = 32; off >= 1; off >>= 1) k += __shfl_xor(k, off);
    float ktot = __shfl(k, 0);
    int batch = t >> 2, ch = t & 3;
    float c = 0.f, v = 0.f;
    for (int i = 0; i < 4; ++i) {
        int blk = batch * 16 + ch * 4 + i;
        c += predp[2 * blk];
        v += predp[2 * blk + 1];
    }
    c += __shfl_xor(c, 1); c += __shfl_xor(c, 2);
    v += __shfl_xor(v, 1); v += __shfl_xor(v, 2);
    int mode = get_mode(detp);
    if ((t & 3) == 0) {
        float d = v, nm = c;
        if (!(d > 0.f)) d = 1.f;
        if (isnan(nm) || isinf(nm)) nm = 0.f;
        float val = 1.f / (1.f + __expf(-nm / d));
        if (mode) ((float*)outv)[batch] = val;
        else      ((u16*)outv)[batch]   = f2bf(val);
    }
    if (t == 1) {
        float val = ktot * (1.f / 16.f);
        if (isnan(val) || isinf(val)) val = 0.f;
        if (mode) ((float*)outv)[16] = val;
        else      ((u16*)outv)[16]   = f2bf(val);
    }
}

// ---------------------------------------------------------------------------
extern "C" void kernel_launch(void* const* d_in, const int* in_sizes, int n_in,
                              void* d_out, int out_size, void* d_ws, size_t ws_size,
                              hipStream_t stream) {
    const int* shape_idxs = (const int*)d_in[0];
    const int* color_idxs = (const int*)d_in[1];
    char* ws = (char*)d_ws;
    const size_t MB = 1024 * 1024;

    if (ws_size < 90 * MB) {
        int wsMB = (int)(ws_size >> 20); if (wsMB > 250) wsMB = 250;
        k_sentinel_f32<<<1, 32, 0, stream>>>((float*)d_out, 200 + wsMB);
        return;
    }

    // ---- arena ----
    u16*   X     = (u16*)(ws);
    u16*   QKVb  = (u16*)(ws + 8 * MB);
    u16*   VT    = (u16*)(ws + 32 * MB);
    u16*   CTX   = (u16*)(ws + 40 * MB);
    u16*   Y1    = (u16*)(ws + 64 * MB);
    u16*   Hb    = (u16*)(ws);
    u16*   FFO   = (u16*)(ws + 72 * MB);
    u16*   Y2    = (u16*)(ws);
    u16*   MEANS = (u16*)(ws + 24 * MB);
    int*   FLAGS = (int*)(ws + 80 * MB);
    int*   SEG   = (int*)(ws + 80 * MB + 65536);
    float* CNT   = (float*)(ws + 80 * MB + 131072);
    float* KLP   = (float*)(ws + 80 * MB + 262144);
    float* PREDP = (float*)(ws + 80 * MB + 327680);
    u16*   W3T   = (u16*)(ws + 81 * MB);
    u16*   WoT   = (u16*)(ws + 81 * MB + 786432);
    u16*   Wp1T  = (u16*)(ws + 81 * MB + 917504);
    u16*   W1T   = (u16*)(ws + 82 * MB);
    u16*   W2T   = (u16*)(ws + 83 * MB);
    int*   DETP  = (int*)(ws + 84 * MB);
    u16*   ING   = (u16*)(ws + 85 * MB);

    const float QSCALE = 0.125f * 1.44269504f;

    // prep table: 7 transposes + 17 small-tensor ingests + 2048 embed blocks
    PrepTab tt;
    const void* tsrc[7] = {d_in[4], d_in[6], d_in[8], d_in[10], d_in[22], d_in[14], d_in[16]};
    u16* tdst[7] = {W3T, W3T + 256 * 256, W3T + 512 * 256, WoT, Wp1T, W1T, W2T};
    int tK[7] = {256, 256, 256, 256, 256, 256, 2048};
    int tN[7] = {256, 256, 256, 256, 256, 2048, 256};
    int ts = 0;
    for (int i = 0; i < 7; ++i) {
        tt.src[i] = tsrc[i]; tt.dst[i] = tdst[i]; tt.K[i] = tK[i]; tt.N[i] = tN[i];
        tt.scale[i] = (i == 0) ? QSCALE : 1.0f;
        tt.tstart[i] = ts;
        ts += (tK[i] >> 5) * (tN[i] >> 5);
    }
    tt.tstart[7] = ts;

    static const int II[17]  = {5, 7, 9, 11, 12, 13, 15, 17, 18, 19, 20, 21, 23, 24, 25, 26, 27};
    static const int IN[17]  = {256, 256, 256, 256, 256, 256, 2048, 256, 256, 256, 768, 3, 256, 256, 1, 1, 1};
    unsigned off = 0;
    for (int i = 0; i < 17; ++i) {
        tt.isrc[i] = d_in[II[i]];
        tt.in[i] = IN[i];
        tt.iscale[i] = 1.0f;
        if (i == 0) { tt.idstoff[0] = off; off += 768; }
        else if (i == 1) tt.idstoff[1] = tt.idstoff[0] + 256;
        else if (i == 2) tt.idstoff[2] = tt.idstoff[0] + 512;
        else { tt.idstoff[i] = off; off += (unsigned)((IN[i] + 8) & ~7); }
    }
    tt.iscale[0] = QSCALE;   // bq
    tt.ing = ING;
    tt.estart = ts + 17;
    tt.si = shape_idxs; tt.ci = color_idxs;
    tt.se = d_in[2]; tt.ce = d_in[3]; tt.X = X;
    const u16* ib3  = ING + tt.idstoff[0];
    const u16* ibo  = ING + tt.idstoff[3];
    const u16* ig1  = ING + tt.idstoff[4];  const u16* ibe1 = ING + tt.idstoff[5];
    const u16* ibf1 = ING + tt.idstoff[6];  const u16* ibf2 = ING + tt.idstoff[7];
    const u16* ig2  = ING + tt.idstoff[8];  const u16* ibe2 = ING + tt.idstoff[9];
    const u16* iWl  = ING + tt.idstoff[10]; const u16* ibl  = ING + tt.idstoff[11];
    const u16* ibp1 = ING + tt.idstoff[12]; const u16* iWp2 = ING + tt.idstoff[13];
    const u16* ibp2 = ING + tt.idstoff[14]; const u16* iwc  = ING + tt.idstoff[15];
    const u16* ibc  = ING + tt.idstoff[16];

    // 0) detect (plain partials)
    k_detect<<<64, 256, 0, stream>>>((const u16*)d_in[14], DETP);
    // 1) prep: transposes + small ingest + embedding, one launch
    k_prep<<<ts + 17 + 2048, 256, 0, stream>>>(tt, DETP);
    // 2) fused QKV projection; V columns written directly in VT layout
    k_gemm64<<<1536, 256, 0, stream>>>(X, W3T, ib3, QKVb, 768, 256, 0, 6, 32, VT);
    // 3) attention
    k_attn_mfma<<<1024, 256, 0, stream>>>(QKVb, VT, CTX);
    // 4) fused Wo GEMM + residual + LN1 -> Y1
    k_wo_ln<<<1024, 256, 0, stream>>>(CTX, WoT, ibo, X, ig1, ibe1, Y1);
    // 5) FFN: FFN1 128-tile (r23 measured config), FFN2 64x64 high-TLP
    k_gemm_bt<<<16 * 128, 256, 0, stream>>>(Y1, W1T, ibf1, Hb, 2048, 256, 1, 16);
    k_gemm64n<<<1024, 256, 0, stream>>>(Hb, W2T, ibf2, FFO, 256, 2048, 0, 4, 32, nullptr);
    // 6) LN2 + logits / KL / flags (fused; writes Y2, KL partials)
    k_logits<<<1024, 256, 0, stream>>>(FFO, Y1, ig2, ibe2, iWl, ibl, Y2, KLP, FLAGS);
    // 7) per-batch exclusive scan
    k_scan<<<16, 1024, 0, stream>>>(FLAGS, SEG);
    // 8) segment means (4 segments per block)
    k_segmean<<<4096, 256, 0, stream>>>(Y2, SEG, MEANS, CNT);
    // 9) fused predicate head (GEMM + Wp2 dot + sigmoid + partials)
    k_predhead<<<256, 256, 0, stream>>>(MEANS, Wp1T, ibp1, iWp2, ibp2, iwc, ibc, CNT, PREDP);
    // 10) finalize + store
    k_final<<<1, 64, 0, stream>>>(PREDP, KLP, DETP, d_out);
}

// Round 10
// 274.350 us; speedup vs baseline: 1.0904x; 1.0309x over previous
//
#include <hip/hip_runtime.h>

// ---------------------------------------------------------------------------
// B=16, L=1024, D=256, H=4 (DH=64), DFF=2048, C=3. Output: 17 elems.
// Dtype-adaptive (f32 or bf16 inputs; mode from DETP partial sums). Wq/bq
// pre-scaled by 0.125*log2e so attention softmax is bare exp2.
// r27: ISOLATED test of k_gemm_bt 2-phase dbuf (r20 bundled it with Q/N
// half-burst changes that likely caused that round's regression): full
// 4-load bursts kept, alternating As/Bs buffers, ONE barrier per 32-slice
// (8 drains instead of 16), each drain hidden under 16 MFMAs of the other
// buffer. LDS 16->32KB (kernel measured 2 blocks/CU effective; 160/32=5).
// K-ascending MFMA order unchanged -> bit-identical Hb. Everything else
// pinned at r26 (282.8us best): attn raw v_exp_f32, segmean 4-seg/block,
// prep+embed merge, predhead fusion, k_wo_ln, r19 attn dbuf, r18 in-reg P.
// 12 launches.
// ---------------------------------------------------------------------------

typedef unsigned short u16;
typedef u16    u16x4  __attribute__((ext_vector_type(4)));
typedef u16    u16x8  __attribute__((ext_vector_type(8)));
typedef __bf16 bf16x8 __attribute__((ext_vector_type(8)));
typedef float  f32x4  __attribute__((ext_vector_type(4)));

__device__ __forceinline__ float bf2f(u16 u) {
    union { unsigned int i; float f; } v; v.i = ((unsigned int)u) << 16; return v.f;
}
__device__ __forceinline__ u16 f2bf(float f) {
    union { float f; unsigned int i; } v; v.f = f;
    unsigned int r = (v.i + 0x7FFFu + ((v.i >> 16) & 1u)) >> 16;
    return (u16)r;
}
__device__ __forceinline__ u16 f2bf_fast(float f) {
    union { __bf16 h; u16 u; } v; v.h = (__bf16)f; return v.u;
}
__device__ __forceinline__ void gll16(const u16* g, u16* l) {
    __builtin_amdgcn_global_load_lds((__attribute__((address_space(1))) void*)(u16*)g,
                                     (__attribute__((address_space(3))) void*)l, 16, 0, 0);
}
__device__ __forceinline__ int get_mode(const int* __restrict__ detp) {
    int s = 0;
#pragma unroll 8
    for (int i = 0; i < 64; ++i) s += detp[i];
    return s > 16;
}

// ---------------- dtype detection: plain per-block partials ----------------
__global__ __launch_bounds__(256) void k_detect(const u16* __restrict__ w1raw,
                                                int* __restrict__ detp) {
    int i = blockIdx.x * 256 + threadIdx.x;
    int bad = 0;
    for (int k = i; k < 65536; k += 64 * 256) {
        unsigned v = w1raw[k] & 0x7FFFu;
        if (v >= 0x7F80u) bad++;
    }
    for (int off = 32; off >= 1; off >>= 1) bad += __shfl_xor(bad, off);
    __shared__ int bs[4];
    if ((threadIdx.x & 63) == 0) bs[threadIdx.x >> 6] = bad;
    __syncthreads();
    if (threadIdx.x == 0) detp[blockIdx.x] = bs[0] + bs[1] + bs[2] + bs[3];
}
__global__ void k_sentinel_f32(float* __restrict__ out, int code) {
    int t = threadIdx.x;
    if (t < 17) out[t] = (float)code;
}

// ------- prep: transposes + small ingest + embedding, one launch -----------
struct PrepTab {
    const void* src[7];
    u16*        dst[7];
    int         K[7], N[7];
    float       scale[7];
    int         tstart[8];     // transpose tile ranges; ingest = [tstart[7], +17)
    const void* isrc[17];
    unsigned    idstoff[17];
    int         in[17];
    float       iscale[17];
    u16*        ing;
    int         estart;        // embed blocks start here
    const int*  si;
    const int*  ci;
    const void* se;
    const void* ce;
    u16*        X;
};
__global__ __launch_bounds__(256) void k_prep(PrepTab tt, const int* __restrict__ detp) {
    int m = get_mode(detp);
    int bx = blockIdx.x;
    if (bx >= tt.estart) {                    // ---- embedding ----
        int t = (bx - tt.estart) * 256 + threadIdx.x;
        int row = t >> 5, seg = (t & 31) * 8;
        int s = tt.si[row], c = tt.ci[row];
        u16x8 o;
        if (m) {
            const float* sp = (const float*)tt.se + s * 256 + seg;
            const float* cp = (const float*)tt.ce + c * 256 + seg;
#pragma unroll
            for (int e = 0; e < 8; ++e) o[e] = f2bf(sp[e] + cp[e]);
        } else {
            u16x8 a = *(const u16x8*)((const u16*)tt.se + s * 256 + seg);
            u16x8 b = *(const u16x8*)((const u16*)tt.ce + c * 256 + seg);
#pragma unroll
            for (int e = 0; e < 8; ++e) o[e] = f2bf(bf2f(a[e]) + bf2f(b[e]));
        }
        *(u16x8*)&tt.X[(size_t)row * 256 + seg] = o;
        return;
    }
    if (bx >= tt.tstart[7]) {                 // ---- small-tensor ingest ----
        int t = bx - tt.tstart[7];
        int n = tt.in[t];
        float sc = tt.iscale[t];
        u16* dst = tt.ing + tt.idstoff[t];
        for (int i = threadIdx.x; i < n; i += 256) {
            float v = m ? ((const float*)tt.isrc[t])[i] : bf2f(((const u16*)tt.isrc[t])[i]);
            dst[i] = f2bf(v * sc);
        }
        return;
    }
    __shared__ u16 tile[32][33];
    int wgt = 0;
#pragma unroll
    for (int i = 1; i < 7; ++i) if (bx >= tt.tstart[i]) wgt = i;
    int local = bx - tt.tstart[wgt];
    int K = tt.K[wgt], N = tt.N[wgt];
    float sc = tt.scale[wgt];
    int ntx = N >> 5;
    int txt = local % ntx, tyt = local / ntx;
    const void* W = tt.src[wgt];
    u16* Wt = tt.dst[wgt];
    int tx = threadIdx.x & 31, ty = threadIdx.x >> 5;
    int n = txt * 32 + tx;
    for (int i = ty; i < 32; i += 8) {
        size_t idx = (size_t)(tyt * 32 + i) * N + n;
        float v = m ? ((const float*)W)[idx] : bf2f(((const u16*)W)[idx]);
        tile[i][tx] = f2bf(v * sc);
    }
    __syncthreads();
    int k2 = tyt * 32 + tx;
    for (int i = ty; i < 32; i += 8) {
        int n2 = txt * 32 + i;
        Wt[(size_t)n2 * K + k2] = tile[tx][i];
    }
}

// ---------------- MFMA GEMM 128x128, gll16, XCD-banded (FFN1) --------------
// r27: 2-phase dbuf — full 4-load burst into the other buffer right after
// the barrier, then compute current buffer; ONE barrier per 32-slice.
__global__ __launch_bounds__(256) void k_gemm_bt(const u16* __restrict__ A,
                                                 const u16* __restrict__ Bt,
                                                 const u16* __restrict__ bias,
                                                 u16* __restrict__ C,
                                                 int N, int K, int relu, int gx) {
    __shared__ u16 As[2][128][32];
    __shared__ u16 Bs[2][128][32];
    const int tid = threadIdx.x;
    const int xcd = blockIdx.x & 7, j = blockIdx.x >> 3;
    const int m0 = (xcd * 16 + j / gx) * 128, n0 = (j % gx) * 128;
    const int lane = tid & 63, wid = tid >> 6;
    const int wm = (wid & 1) * 64, wn = (wid >> 1) * 64;
    const int m16 = lane & 15, quad = lane >> 4;
    f32x4 acc[4][4] = {};
    const int arow = tid >> 2;
    const int ac8  = (tid & 3) * 8;
    const u16* Ap0 = A  + (size_t)(m0 + arow) * K + ac8;
    const u16* Ap1 = A  + (size_t)(m0 + 64 + arow) * K + ac8;
    const u16* Bp0 = Bt + (size_t)(n0 + arow) * K + ac8;
    const u16* Bp1 = Bt + (size_t)(n0 + 64 + arow) * K + ac8;

#define BT_STAGE(bi, k0) do {                       \
    gll16(Ap0 + (k0), &As[bi][arow][ac8]);          \
    gll16(Ap1 + (k0), &As[bi][64 + arow][ac8]);     \
    gll16(Bp0 + (k0), &Bs[bi][arow][ac8]);          \
    gll16(Bp1 + (k0), &Bs[bi][64 + arow][ac8]);     \
} while (0)

#define BT_COMP(bi) do {                                                   \
    bf16x8 af[4], bfv[4];                                                  \
    _Pragma("unroll")                                                      \
    for (int i = 0; i < 4; ++i)                                            \
        af[i] = *(const bf16x8*)&As[bi][wm + i * 16 + m16][quad * 8];      \
    _Pragma("unroll")                                                      \
    for (int j2 = 0; j2 < 4; ++j2)                                         \
        bfv[j2] = *(const bf16x8*)&Bs[bi][wn + j2 * 16 + m16][quad * 8];   \
    _Pragma("unroll")                                                      \
    for (int i = 0; i < 4; ++i)                                            \
        _Pragma("unroll")                                                  \
        for (int j2 = 0; j2 < 4; ++j2)                                     \
            acc[i][j2] = __builtin_amdgcn_mfma_f32_16x16x32_bf16(          \
                af[i], bfv[j2], acc[i][j2], 0, 0, 0);                      \
} while (0)

    BT_STAGE(0, 0);
    for (int k0 = 0; k0 < K; k0 += 64) {
        __syncthreads();
        if (k0 + 32 < K) BT_STAGE(1, k0 + 32);
        BT_COMP(0);
        __syncthreads();
        if (k0 + 64 < K) BT_STAGE(0, k0 + 64);
        BT_COMP(1);
    }
#undef BT_STAGE
#undef BT_COMP

#pragma unroll
    for (int i = 0; i < 4; ++i) {
        int row = m0 + wm + i * 16 + quad * 4;
#pragma unroll
        for (int j2 = 0; j2 < 4; ++j2) {
            int col = n0 + wn + j2 * 16 + m16;
            float bv = bf2f(bias[col]);
#pragma unroll
            for (int r = 0; r < 4; ++r) {
                float v = acc[i][j2][r] + bv;
                if (relu) v = fmaxf(v, 0.f);
                C[(size_t)(row + r) * N + col] = f2bf_fast(v);
            }
        }
    }
}

// ---------------- MFMA GEMM 64x128, BK=64 (QKV; vt epilogue) ---------------
__global__ __launch_bounds__(256) void k_gemm64(const u16* __restrict__ A,
                                                const u16* __restrict__ Bt,
                                                const u16* __restrict__ bias,
                                                u16* __restrict__ C,
                                                int N, int K, int relu,
                                                int gx, int mtpx,
                                                u16* __restrict__ vt) {
    __shared__ u16 As0[64][32], As1[64][32];
    __shared__ u16 Bs0[128][32], Bs1[128][32];
    const int tid = threadIdx.x;
    const int xcd = blockIdx.x & 7, j = blockIdx.x >> 3;
    const int m0 = (xcd * mtpx + j / gx) * 64, n0 = (j % gx) * 128;
    const int vmode = (vt != nullptr) && (n0 >= 512);
    const int lane = tid & 63, wid = tid >> 6;
    const int wm = (wid & 1) * 32, wn = (wid >> 1) * 64;
    const int m16 = lane & 15, quad = lane >> 4;
    f32x4 acc[2][4] = {};
    const int arow = tid >> 2;
    const int ac8  = (tid & 3) * 8;
    const u16* Ap  = A  + (size_t)(m0 + arow) * K + ac8;
    const u16* Bp0 = Bt + (size_t)(n0 + arow) * K + ac8;
    const u16* Bp1 = Bt + (size_t)(n0 + 64 + arow) * K + ac8;
    u16* lA0  = &As0[arow][ac8];
    u16* lA1  = &As1[arow][ac8];
    u16* lB00 = &Bs0[arow][ac8];
    u16* lB01 = &Bs0[64 + arow][ac8];
    u16* lB10 = &Bs1[arow][ac8];
    u16* lB11 = &Bs1[64 + arow][ac8];

    for (int k0 = 0; k0 < K; k0 += 64) {
        __syncthreads();
        gll16(Ap + k0,        lA0);
        gll16(Ap + k0 + 32,   lA1);
        gll16(Bp0 + k0,       lB00);
        gll16(Bp0 + k0 + 32,  lB10);
        gll16(Bp1 + k0,       lB01);
        gll16(Bp1 + k0 + 32,  lB11);
        __syncthreads();
#pragma unroll
        for (int ks = 0; ks < 2; ++ks) {
            bf16x8 af[2], bfv[4];
#pragma unroll
            for (int i = 0; i < 2; ++i)
                af[i] = ks == 0 ? *(const bf16x8*)&As0[wm + i * 16 + m16][quad * 8]
                                : *(const bf16x8*)&As1[wm + i * 16 + m16][quad * 8];
#pragma unroll
            for (int j2 = 0; j2 < 4; ++j2)
                bfv[j2] = ks == 0 ? *(const bf16x8*)&Bs0[wn + j2 * 16 + m16][quad * 8]
                                  : *(const bf16x8*)&Bs1[wn + j2 * 16 + m16][quad * 8];
#pragma unroll
            for (int i = 0; i < 2; ++i)
#pragma unroll
                for (int j2 = 0; j2 < 4; ++j2)
                    acc[i][j2] = __builtin_amdgcn_mfma_f32_16x16x32_bf16(
                        af[i], bfv[j2], acc[i][j2], 0, 0, 0);
        }
    }

#pragma unroll
    for (int i = 0; i < 2; ++i) {
        int row = m0 + wm + i * 16 + quad * 4;
#pragma unroll
        for (int j2 = 0; j2 < 4; ++j2) {
            int col = n0 + wn + j2 * 16 + m16;
            float bv = bf2f(bias[col]);
            if (vmode) {
                int ch = col - 512;
                u16x4 o;
#pragma unroll
                for (int r = 0; r < 4; ++r) o[r] = f2bf_fast(acc[i][j2][r] + bv);
                size_t vb = ((size_t)((row >> 10) * 4 + (ch >> 6)) * 64 + (ch & 63)) * 1024
                          + (row & 1023);
                *(u16x4*)&vt[vb] = o;
            } else {
#pragma unroll
                for (int r = 0; r < 4; ++r) {
                    float v = acc[i][j2][r] + bv;
                    if (relu) v = fmaxf(v, 0.f);
                    C[(size_t)(row + r) * N + col] = f2bf_fast(v);
                }
            }
        }
    }
}

// ---------------- MFMA GEMM 64x64, BK=64 — high-TLP (FFN2) -----------------
__global__ __launch_bounds__(256) void k_gemm64n(const u16* __restrict__ A,
                                                 const u16* __restrict__ Bt,
                                                 const u16* __restrict__ bias,
                                                 u16* __restrict__ C,
                                                 int N, int K, int relu,
                                                 int gnx, int mtpx,
                                                 const float* __restrict__ gate) {
    __shared__ u16 As0[64][32], As1[64][32];
    __shared__ u16 Bs0[64][32], Bs1[64][32];
    const int tid = threadIdx.x;
    const int xcd = blockIdx.x & 7, j = blockIdx.x >> 3;
    const int m0 = (xcd * mtpx + j / gnx) * 64, n0 = (j % gnx) * 64;
    if (gate && gate[m0] == 0.f) return;
    const int lane = tid & 63, w = tid >> 6;
    const int m16 = lane & 15, quad = lane >> 4;
    f32x4 acc[4] = {};
    const int arow = tid >> 2;          // 0..63
    const int ac8  = (tid & 3) * 8;     // 0,8,16,24
    const u16* Ap = A  + (size_t)(m0 + arow) * K + ac8;
    const u16* Bp = Bt + (size_t)(n0 + arow) * K + ac8;
    u16* lA0 = &As0[arow][ac8];
    u16* lA1 = &As1[arow][ac8];
    u16* lB0 = &Bs0[arow][ac8];
    u16* lB1 = &Bs1[arow][ac8];

    for (int k0 = 0; k0 < K; k0 += 64) {
        __syncthreads();
        gll16(Ap + k0,       lA0);
        gll16(Ap + k0 + 32,  lA1);
        gll16(Bp + k0,       lB0);
        gll16(Bp + k0 + 32,  lB1);
        __syncthreads();
#pragma unroll
        for (int ks = 0; ks < 2; ++ks) {
            bf16x8 af = ks == 0 ? *(const bf16x8*)&As0[w * 16 + m16][quad * 8]
                                : *(const bf16x8*)&As1[w * 16 + m16][quad * 8];
#pragma unroll
            for (int nt = 0; nt < 4; ++nt) {
                bf16x8 bfv = ks == 0 ? *(const bf16x8*)&Bs0[nt * 16 + m16][quad * 8]
                                     : *(const bf16x8*)&Bs1[nt * 16 + m16][quad * 8];
                acc[nt] = __builtin_amdgcn_mfma_f32_16x16x32_bf16(af, bfv, acc[nt], 0, 0, 0);
            }
        }
    }

#pragma unroll
    for (int nt = 0; nt < 4; ++nt) {
        int col = n0 + nt * 16 + m16;
        float bv = bf2f(bias[col]);
        int row = m0 + w * 16 + quad * 4;
#pragma unroll
        for (int r = 0; r < 4; ++r) {
            float v = acc[nt][r] + bv;
            if (relu) v = fmaxf(v, 0.f);
            C[(size_t)(row + r) * N + col] = f2bf_fast(v);
        }
    }
}

// ---------------------------------------------------------------------------
// r22: fused Wo-GEMM + residual + LayerNorm1 (validated). 16x256 tile/block.
// ---------------------------------------------------------------------------
__global__ __launch_bounds__(256) void k_wo_ln(const u16* __restrict__ A,
                                               const u16* __restrict__ Bt,
                                               const u16* __restrict__ bias,
                                               const u16* __restrict__ X,
                                               const u16* __restrict__ g,
                                               const u16* __restrict__ be,
                                               u16* __restrict__ Y1) {
    __shared__ u16 As0[16][32], As1[16][32];
    __shared__ u16 Bs0[256][32], Bs1[256][32];
    __shared__ float lnp[2][4][16];
    const int tid = threadIdx.x, lane = tid & 63, w = tid >> 6;
    const int m16 = lane & 15, quad = lane >> 4;
    const int xcd = blockIdx.x & 7, j = blockIdx.x >> 3;
    const int m0 = (xcd * 128 + j) * 16;
    const int K = 256;
    f32x4 acc[4] = {};
    const int an = lane >> 2, ac = (lane & 3) * 8;

    for (int k0 = 0; k0 < K; k0 += 64) {
        __syncthreads();
#pragma unroll
        for (int i = 0; i < 4; ++i) {
            int ch = i * 256 + tid;
            int n = ch >> 2, kc = (ch & 3) * 8;
            gll16(Bt + (size_t)n * K + k0 + kc,      &Bs0[n][kc]);
            gll16(Bt + (size_t)n * K + k0 + 32 + kc, &Bs1[n][kc]);
        }
        if (w == 0) gll16(A + (size_t)(m0 + an) * K + k0 + ac,      &As0[an][ac]);
        if (w == 1) gll16(A + (size_t)(m0 + an) * K + k0 + 32 + ac, &As1[an][ac]);
        __syncthreads();
#pragma unroll
        for (int ks = 0; ks < 2; ++ks) {
            bf16x8 af = ks == 0 ? *(const bf16x8*)&As0[m16][quad * 8]
                                : *(const bf16x8*)&As1[m16][quad * 8];
#pragma unroll
            for (int nt = 0; nt < 4; ++nt) {
                bf16x8 bfv = ks == 0
                    ? *(const bf16x8*)&Bs0[w * 64 + nt * 16 + m16][quad * 8]
                    : *(const bf16x8*)&Bs1[w * 64 + nt * 16 + m16][quad * 8];
                acc[nt] = __builtin_amdgcn_mfma_f32_16x16x32_bf16(af, bfv, acc[nt], 0, 0, 0);
            }
        }
    }

    float vln[4][4];
    float s[4] = {0.f, 0.f, 0.f, 0.f}, sq[4] = {0.f, 0.f, 0.f, 0.f};
#pragma unroll
    for (int nt = 0; nt < 4; ++nt) {
        int col = w * 64 + nt * 16 + m16;
        float bv = bf2f(bias[col]);
#pragma unroll
        for (int r = 0; r < 4; ++r) {
            int row = m0 + quad * 4 + r;
            u16 c16 = f2bf_fast(acc[nt][r] + bv);
            float v = bf2f(c16) + bf2f(X[(size_t)row * 256 + col]);
            vln[nt][r] = v;
            s[r] += v; sq[r] += v * v;
        }
    }
#pragma unroll
    for (int r = 0; r < 4; ++r)
        for (int off = 1; off < 16; off <<= 1) {
            s[r]  += __shfl_xor(s[r], off);
            sq[r] += __shfl_xor(sq[r], off);
        }
    if (m16 == 0) {
#pragma unroll
        for (int r = 0; r < 4; ++r) {
            lnp[0][w][quad * 4 + r] = s[r];
            lnp[1][w][quad * 4 + r] = sq[r];
        }
    }
    __syncthreads();
#pragma unroll
    for (int r = 0; r < 4; ++r) {
        int rw = quad * 4 + r;
        float st  = lnp[0][0][rw] + lnp[0][1][rw] + lnp[0][2][rw] + lnp[0][3][rw];
        float sqt = lnp[1][0][rw] + lnp[1][1][rw] + lnp[1][2][rw] + lnp[1][3][rw];
        float mean = st * (1.f / 256.f);
        float var  = sqt * (1.f / 256.f) - mean * mean;
        float rs   = rsqrtf(var + 1e-5f);
        int row = m0 + rw;
#pragma unroll
        for (int nt = 0; nt < 4; ++nt) {
            int col = w * 64 + nt * 16 + m16;
            Y1[(size_t)row * 256 + col] =
                f2bf((vln[nt][r] - mean) * rs * bf2f(g[col]) + bf2f(be[col]));
        }
    }
}

// ---------------------------------------------------------------------------
// r23: fused predicate head — 64x256-tile GEMM (relu(means@Wp1+bp1)) with
// in-block Wp2 dot + sigmoid + per-block comp partials.
// ---------------------------------------------------------------------------
__global__ __launch_bounds__(256) void k_predhead(const u16* __restrict__ A,
                                                  const u16* __restrict__ Bt,
                                                  const u16* __restrict__ bp1,
                                                  const u16* __restrict__ Wp2,
                                                  const u16* __restrict__ bp2,
                                                  const u16* __restrict__ wc,
                                                  const u16* __restrict__ bc,
                                                  const float* __restrict__ cnt,
                                                  float* __restrict__ predp) {
    const int tid = threadIdx.x;
    const int m0 = blockIdx.x * 64;
    if (cnt[m0] == 0.f) {
        if (tid == 0) { predp[2 * blockIdx.x] = 0.f; predp[2 * blockIdx.x + 1] = 0.f; }
        return;
    }
    __shared__ u16 As0[64][32], As1[64][32];
    __shared__ u16 Bs0[256][32], Bs1[256][32];
    __shared__ float cs[4], vs[4];
    const int lane = tid & 63, w = tid >> 6;
    const int m16 = lane & 15, quad = lane >> 4;
    f32x4 acc[16] = {};
    const int ar = tid >> 2, akc = (tid & 3) * 8;

    for (int k0 = 0; k0 < 256; k0 += 64) {
        __syncthreads();
        gll16(A + (size_t)(m0 + ar) * 256 + k0 + akc,      &As0[ar][akc]);
        gll16(A + (size_t)(m0 + ar) * 256 + k0 + 32 + akc, &As1[ar][akc]);
#pragma unroll
        for (int i = 0; i < 4; ++i) {
            int ch = i * 256 + tid;
            int n = ch >> 2, kc = (ch & 3) * 8;
            gll16(Bt + (size_t)n * 256 + k0 + kc,      &Bs0[n][kc]);
            gll16(Bt + (size_t)n * 256 + k0 + 32 + kc, &Bs1[n][kc]);
        }
        __syncthreads();
#pragma unroll
        for (int ks = 0; ks < 2; ++ks) {
            bf16x8 af = ks == 0 ? *(const bf16x8*)&As0[w * 16 + m16][quad * 8]
                                : *(const bf16x8*)&As1[w * 16 + m16][quad * 8];
#pragma unroll
            for (int nt = 0; nt < 16; ++nt) {
                bf16x8 bfv = ks == 0 ? *(const bf16x8*)&Bs0[nt * 16 + m16][quad * 8]
                                     : *(const bf16x8*)&Bs1[nt * 16 + m16][quad * 8];
                acc[nt] = __builtin_amdgcn_mfma_f32_16x16x32_bf16(af, bfv, acc[nt], 0, 0, 0);
            }
        }
    }

    const float fb = bf2f(bp2[0]), fw = bf2f(wc[0]), fc = bf2f(bc[0]);
    float part[4] = {0.f, 0.f, 0.f, 0.f};
#pragma unroll
    for (int nt = 0; nt < 16; ++nt) {
        int col = nt * 16 + m16;
        float bv = bf2f(bp1[col]);
        float wp = bf2f(Wp2[col]);
#pragma unroll
        for (int r = 0; r < 4; ++r) {
            float t = fmaxf(acc[nt][r] + bv, 0.f);
            part[r] += bf2f(f2bf_fast(t)) * wp;   // replicate TB bf16 round-trip
        }
    }
#pragma unroll
    for (int r = 0; r < 4; ++r)
        for (int off = 1; off < 16; off <<= 1)
            part[r] += __shfl_xor(part[r], off);

    float csum = 0.f, vsum = 0.f;
    if (m16 == 0) {
#pragma unroll
        for (int r = 0; r < 4; ++r) {
            int row = m0 + w * 16 + quad * 4 + r;
            if (cnt[row] > 0.f) {
                float pred = 1.f / (1.f + __expf(-(part[r] + fb)));
                csum += pred * fw + fc;
                vsum += 1.f;
            }
        }
    }
    csum += __shfl_xor(csum, 16); csum += __shfl_xor(csum, 32);
    vsum += __shfl_xor(vsum, 16); vsum += __shfl_xor(vsum, 32);
    if (lane == 0) { cs[w] = csum; vs[w] = vsum; }
    __syncthreads();
    if (tid == 0) {
        predp[2 * blockIdx.x]     = cs[0] + cs[1] + cs[2] + cs[3];
        predp[2 * blockIdx.x + 1] = vs[0] + vs[1] + vs[2] + vs[3];
    }
}

// ---------------------------------------------------------------------------
// MFMA flash attention — r19 structure; r26 raw v_exp_f32. In-register P via
// swapped QK^T (mfma(K,Q)) + key-slot permutation; K stored at
// bit2<->bit3-swapped rows. 36.9KB LDS, 4 blocks/CU, 1024 blocks.
// ---------------------------------------------------------------------------
__global__ __launch_bounds__(256) void k_attn_mfma(const u16* __restrict__ QKV,
                                                   const u16* __restrict__ VT,
                                                   u16* __restrict__ CTX) {
    __shared__ u16 Ks[2][64][72];
    __shared__ u16 Vts[2][64][72];
    const int tid = threadIdx.x, lane = tid & 63, w = tid >> 6;
    const int quad = lane >> 4, c = lane & 15;
    const int blk = blockIdx.x;
    const int xcd = blk & 7, local = blk >> 3;
    const int bh = xcd * 8 + (local >> 4);
    const int qt = local & 15;
    const int b = bh >> 2, h = bh & 3;
    const int qrow0 = b * 1024 + qt * 64;

    const u16* qptr = QKV + (size_t)(qrow0 + w * 16 + c) * 768 + h * 64;
    bf16x8 aq0 = *(const bf16x8*)(qptr + quad * 8);
    bf16x8 aq1 = *(const bf16x8*)(qptr + 32 + quad * 8);

    bf16x8 ones;
    {
        union { u16 u; __bf16 h; } v; v.u = 0x3F80;
#pragma unroll
        for (int e = 0; e < 8; ++e) ones[e] = v.h;
    }

    f32x4 acc_o[4] = {};
    f32x4 acc_l = {};

    const u16* kbase  = QKV + (size_t)(b * 1024) * 768 + 256 + h * 64;
    const u16* vtbase = VT + (size_t)(bh * 64) * 1024;
    const int skk = tid >> 3, sc8 = (tid & 7) * 8;
    const int swk = (skk & ~12) | ((skk & 4) << 1) | ((skk & 8) >> 1);
    const int sra = ((c & 8) << 1) | (c & 4) | (c & 3);

    u16x8 rk0, rk1, rv0, rv1;

#define LOADT(t) do {                                                          \
    rk0 = *(const u16x8*)(kbase + (size_t)((t) * 64 + skk) * 768 + sc8);       \
    rk1 = *(const u16x8*)(kbase + (size_t)((t) * 64 + skk + 32) * 768 + sc8);  \
    rv0 = *(const u16x8*)(vtbase + (size_t)skk * 1024 + (t) * 64 + sc8);       \
    rv1 = *(const u16x8*)(vtbase + (size_t)(skk + 32) * 1024 + (t) * 64 + sc8);\
} while (0)

#define STORET(bi) do {                                                        \
    *(u16x8*)&Ks[bi][swk][sc8]       = rk0;                                    \
    *(u16x8*)&Ks[bi][swk + 32][sc8]  = rk1;                                    \
    *(u16x8*)&Vts[bi][skk][sc8]      = rv0;                                    \
    *(u16x8*)&Vts[bi][skk + 32][sc8] = rv1;                                    \
} while (0)

#define COMPUTE(bi) do {                                                        \
    _Pragma("unroll")                                                           \
    for (int ks = 0; ks < 2; ++ks) {                                            \
        const int ra = ks * 32 + sra;                                           \
        bf16x8 ka0 = *(const bf16x8*)&Ks[bi][ra][quad * 8];                     \
        bf16x8 ka1 = *(const bf16x8*)&Ks[bi][ra][32 + quad * 8];                \
        bf16x8 kb0 = *(const bf16x8*)&Ks[bi][ra + 8][quad * 8];                 \
        bf16x8 kb1 = *(const bf16x8*)&Ks[bi][ra + 8][32 + quad * 8];            \
        f32x4 za = {}, zb = {};                                                 \
        za = __builtin_amdgcn_mfma_f32_16x16x32_bf16(ka0, aq0, za, 0, 0, 0);    \
        za = __builtin_amdgcn_mfma_f32_16x16x32_bf16(ka1, aq1, za, 0, 0, 0);    \
        zb = __builtin_amdgcn_mfma_f32_16x16x32_bf16(kb0, aq0, zb, 0, 0, 0);    \
        zb = __builtin_amdgcn_mfma_f32_16x16x32_bf16(kb1, aq1, zb, 0, 0, 0);    \
        bf16x8 ap;                                                              \
        _Pragma("unroll")                                                       \
        for (int r = 0; r < 4; ++r) {                                           \
            ap[r]     = (__bf16)__builtin_amdgcn_exp2f(fminf(za[r], 80.f));     \
            ap[4 + r] = (__bf16)__builtin_amdgcn_exp2f(fminf(zb[r], 80.f));     \
        }                                                                       \
        acc_l = __builtin_amdgcn_mfma_f32_16x16x32_bf16(ap, ones, acc_l, 0, 0, 0);\
        _Pragma("unroll")                                                       \
        for (int nt = 0; nt < 4; ++nt) {                                        \
            bf16x8 bv = *(const bf16x8*)&Vts[bi][nt * 16 + c][ks * 32 + quad * 8];\
            acc_o[nt] = __builtin_amdgcn_mfma_f32_16x16x32_bf16(ap, bv, acc_o[nt], 0, 0, 0);\
        }                                                                       \
    }                                                                           \
} while (0)

    LOADT(0);
    STORET(0);
    for (int t = 0; t < 16; t += 2) {
        __syncthreads();
        LOADT(t + 1);
        COMPUTE(0);
        STORET(1);
        __syncthreads();
        if (t + 2 < 16) LOADT(t + 2);
        COMPUTE(1);
        if (t + 2 < 16) STORET(0);
    }

#undef LOADT
#undef STORET
#undef COMPUTE

#pragma unroll
    for (int nt = 0; nt < 4; ++nt) {
        int col = h * 64 + nt * 16 + c;
#pragma unroll
        for (int r = 0; r < 4; ++r) {
            int row = qrow0 + w * 16 + quad * 4 + r;
            CTX[(size_t)row * 256 + col] = f2bf_fast(acc_o[nt][r] / acc_l[r]);
        }
    }
}

// ---------------- LN2 + logits / KL / flags fused (KL partials) ------------
__global__ __launch_bounds__(256) void k_logits(const u16* __restrict__ FFO,
                                                const u16* __restrict__ Y1,
                                                const u16* __restrict__ g2,
                                                const u16* __restrict__ be2,
                                                const u16* __restrict__ Wl,
                                                const u16* __restrict__ bl,
                                                u16* __restrict__ Y2,
                                                float* __restrict__ klpart,
                                                int* __restrict__ flags) {
    const int tid = threadIdx.x, lane = tid & 63, w = tid >> 6;
    float wv[4][3], gv[4], bev[4];
#pragma unroll
    for (int j = 0; j < 4; ++j) {
        int d = lane * 4 + j;
        gv[j]  = bf2f(g2[d]);
        bev[j] = bf2f(be2[d]);
#pragma unroll
        for (int c = 0; c < 3; ++c) wv[j][c] = bf2f(Wl[d * 3 + c]);
    }
    const float b0 = bf2f(bl[0]), b1 = bf2f(bl[1]), b2 = bf2f(bl[2]);
    float klsum = 0.f;
    const int row0 = blockIdx.x * 16 + w * 4;
    for (int i = 0; i < 4; ++i) {
        int row = row0 + i;
        size_t base = (size_t)row * 256 + lane * 4;
        u16x4 f4 = *(const u16x4*)&FFO[base];
        u16x4 y4 = *(const u16x4*)&Y1[base];
        float v[4];
        float s = 0.f, sq = 0.f;
#pragma unroll
        for (int j = 0; j < 4; ++j) {
            v[j] = bf2f(f4[j]) + bf2f(y4[j]);
            s += v[j]; sq += v[j] * v[j];
        }
        for (int off = 32; off >= 1; off >>= 1) { s += __shfl_xor(s, off); sq += __shfl_xor(sq, off); }
        float mean = s * (1.f / 256.f);
        float var  = sq * (1.f / 256.f) - mean * mean;
        float rs   = rsqrtf(var + 1e-5f);
        u16x4 o;
        float a0 = 0.f, a1 = 0.f, a2 = 0.f;
#pragma unroll
        for (int j = 0; j < 4; ++j) {
            float yn = (v[j] - mean) * rs * gv[j] + bev[j];
            o[j] = f2bf(yn);
            float y = bf2f(o[j]);
            a0 += y * wv[j][0]; a1 += y * wv[j][1]; a2 += y * wv[j][2];
        }
        *(u16x4*)&Y2[base] = o;
        for (int off = 32; off >= 1; off >>= 1) {
            a0 += __shfl_xor(a0, off); a1 += __shfl_xor(a1, off); a2 += __shfl_xor(a2, off);
        }
        if (lane == 0) {
            float l0 = a0 + b0, l1 = a1 + b1, l2 = a2 + b2;
            float mx = fmaxf(l0, fmaxf(l1, l2));
            float lse = mx + __logf(__expf(l0 - mx) + __expf(l1 - mx) + __expf(l2 - mx));
            klsum += lse - (l0 + l1 + l2) * (1.f / 3.f) - 1.0986122886681098f;
            int am = 0; float bv = l0;
            if (l1 > bv) { bv = l1; am = 1; }
            if (l2 > bv) { am = 2; }
            int l = row & 1023;
            flags[row] = (am == 0 && l != 0) ? 1 : 0;
        }
    }
    __shared__ float kls[4];
    if (lane == 0) kls[w] = klsum;
    __syncthreads();
    if (tid == 0) klpart[blockIdx.x] = kls[0] + kls[1] + kls[2] + kls[3];
}

// per-batch exclusive scan: wave shuffle-scan, 2 barriers
__global__ void k_scan(const int* __restrict__ flags, int* __restrict__ seg) {
    __shared__ int wsum[16];
    int b = blockIdx.x, t = threadIdx.x;
    int lane = t & 63, w = t >> 6;
    int f = flags[b * 1024 + t];
    int x = f;
#pragma unroll
    for (int off = 1; off < 64; off <<= 1) {
        int v = __shfl_up(x, off);
        if (lane >= off) x += v;
    }
    if (lane == 63) wsum[w] = x;
    __syncthreads();
    if (w == 0) {
        int s = (lane < 16) ? wsum[lane] : 0;
#pragma unroll
        for (int off = 1; off < 16; off <<= 1) {
            int v = __shfl_up(s, off);
            if (lane >= off) s += v;
        }
        if (lane < 16) wsum[lane] = s;
    }
    __syncthreads();
    int prefix = (w > 0) ? wsum[w - 1] : 0;
    seg[b * 1024 + t] = prefix + x - f;
}

// ---------------- segmean: 4 segments per block (one per wave) -------------
__global__ __launch_bounds__(256) void k_segmean(const u16* __restrict__ Y,
                                                 const int* __restrict__ seg,
                                                 u16* __restrict__ means,
                                                 float* __restrict__ cnt) {
    int wv = threadIdx.x >> 6, lane = threadIdx.x & 63;
    int g = blockIdx.x * 4 + wv;
    int b = g >> 10, s = g & 1023;
    const int* sb = seg + b * 1024;
    int target = s + (lane & 1);
    int lo = 0, hi = 1024;
    while (lo < hi) {
        int mid = (lo + hi) >> 1;
        if (sb[mid] < target) lo = mid + 1; else hi = mid;
    }
    int start = __shfl(lo, 0);
    int end   = __shfl(lo, 1);
    int n = end - start;
    if (lane == 0) cnt[g] = (float)n;
    if (n <= 0) return;
    f32x4 acc = {};
    for (int row = start; row < end; ++row) {
        u16x4 y4 = *(const u16x4*)&Y[(size_t)(b * 1024 + row) * 256 + lane * 4];
        acc[0] += bf2f(y4[0]); acc[1] += bf2f(y4[1]);
        acc[2] += bf2f(y4[2]); acc[3] += bf2f(y4[3]);
    }
    float inv = 1.f / (float)n;
    u16x4 o;
#pragma unroll
    for (int j = 0; j < 4; ++j) o[j] = f2bf(acc[j] * inv);
    *(u16x4*)&means[(size_t)g * 256 + lane * 4] = o;
}

// ---------------- finalize: sum KL + pred partials, store ----------------
// predp has 256 entries (16 blocks per batch).
__global__ void k_final(const float* __restrict__ predp, const float* __restrict__ klp,
                        const int* __restrict__ detp, void* __restrict__ outv) {
    int t = threadIdx.x;   // 64
    float k = 0.f;
    for (int i = t; i < 1024; i += 64) k += klp[i];
    for (int off = 32; off >= 1; off >>= 1) k += __shfl_xor(k, off);
    float ktot = __shfl(k, 0);
    int batch = t >> 2, ch = t & 3;
    float c = 0.f, v = 0.f;
    for (int i = 0; i < 4; ++i) {
        int blk = batch * 16 + ch * 4 + i;
        c += predp[2 * blk];
        v += predp[2 * blk + 1];
    }
    c += __shfl_xor(c, 1); c += __shfl_xor(c, 2);
    v += __shfl_xor(v, 1); v += __shfl_xor(v, 2);
    int mode = get_mode(detp);
    if ((t & 3) == 0) {
        float d = v, nm = c;
        if (!(d > 0.f)) d = 1.f;
        if (isnan(nm) || isinf(nm)) nm = 0.f;
        float val = 1.f / (1.f + __expf(-nm / d));
        if (mode) ((float*)outv)[batch] = val;
        else      ((u16*)outv)[batch]   = f2bf(val);
    }
    if (t == 1) {
        float val = ktot * (1.f / 16.f);
        if (isnan(val) || isinf(val)) val = 0.f;
        if (mode) ((float*)outv)[16] = val;
        else      ((u16*)outv)[16]   = f2bf(val);
    }
}

// ---------------------------------------------------------------------------
extern "C" void kernel_launch(void* const* d_in, const int* in_sizes, int n_in,
                              void* d_out, int out_size, void* d_ws, size_t ws_size,
                              hipStream_t stream) {
    const int* shape_idxs = (const int*)d_in[0];
    const int* color_idxs = (const int*)d_in[1];
    char* ws = (char*)d_ws;
    const size_t MB = 1024 * 1024;

    if (ws_size < 90 * MB) {
        int wsMB = (int)(ws_size >> 20); if (wsMB > 250) wsMB = 250;
        k_sentinel_f32<<<1, 32, 0, stream>>>((float*)d_out, 200 + wsMB);
        return;
    }

    // ---- arena ----
    u16*   X     = (u16*)(ws);
    u16*   QKVb  = (u16*)(ws + 8 * MB);
    u16*   VT    = (u16*)(ws + 32 * MB);
    u16*   CTX   = (u16*)(ws + 40 * MB);
    u16*   Y1    = (u16*)(ws + 64 * MB);
    u16*   Hb    = (u16*)(ws);
    u16*   FFO   = (u16*)(ws + 72 * MB);
    u16*   Y2    = (u16*)(ws);
    u16*   MEANS = (u16*)(ws + 24 * MB);
    int*   FLAGS = (int*)(ws + 80 * MB);
    int*   SEG   = (int*)(ws + 80 * MB + 65536);
    float* CNT   = (float*)(ws + 80 * MB + 131072);
    float* KLP   = (float*)(ws + 80 * MB + 262144);
    float* PREDP = (float*)(ws + 80 * MB + 327680);
    u16*   W3T   = (u16*)(ws + 81 * MB);
    u16*   WoT   = (u16*)(ws + 81 * MB + 786432);
    u16*   Wp1T  = (u16*)(ws + 81 * MB + 917504);
    u16*   W1T   = (u16*)(ws + 82 * MB);
    u16*   W2T   = (u16*)(ws + 83 * MB);
    int*   DETP  = (int*)(ws + 84 * MB);
    u16*   ING   = (u16*)(ws + 85 * MB);

    const float QSCALE = 0.125f * 1.44269504f;

    // prep table: 7 transposes + 17 small-tensor ingests + 2048 embed blocks
    PrepTab tt;
    const void* tsrc[7] = {d_in[4], d_in[6], d_in[8], d_in[10], d_in[22], d_in[14], d_in[16]};
    u16* tdst[7] = {W3T, W3T + 256 * 256, W3T + 512 * 256, WoT, Wp1T, W1T, W2T};
    int tK[7] = {256, 256, 256, 256, 256, 256, 2048};
    int tN[7] = {256, 256, 256, 256, 256, 2048, 256};
    int ts = 0;
    for (int i = 0; i < 7; ++i) {
        tt.src[i] = tsrc[i]; tt.dst[i] = tdst[i]; tt.K[i] = tK[i]; tt.N[i] = tN[i];
        tt.scale[i] = (i == 0) ? QSCALE : 1.0f;
        tt.tstart[i] = ts;
        ts += (tK[i] >> 5) * (tN[i] >> 5);
    }
    tt.tstart[7] = ts;

    static const int II[17]  = {5, 7, 9, 11, 12, 13, 15, 17, 18, 19, 20, 21, 23, 24, 25, 26, 27};
    static const int IN[17]  = {256, 256, 256, 256, 256, 256, 2048, 256, 256, 256, 768, 3, 256, 256, 1, 1, 1};
    unsigned off = 0;
    for (int i = 0; i < 17; ++i) {
        tt.isrc[i] = d_in[II[i]];
        tt.in[i] = IN[i];
        tt.iscale[i] = 1.0f;
        if (i == 0) { tt.idstoff[0] = off; off += 768; }
        else if (i == 1) tt.idstoff[1] = tt.idstoff[0] + 256;
        else if (i == 2) tt.idstoff[2] = tt.idstoff[0] + 512;
        else { tt.idstoff[i] = off; off += (unsigned)((IN[i] + 8) & ~7); }
    }
    tt.iscale[0] = QSCALE;   // bq
    tt.ing = ING;
    tt.estart = ts + 17;
    tt.si = shape_idxs; tt.ci = color_idxs;
    tt.se = d_in[2]; tt.ce = d_in[3]; tt.X = X;
    const u16* ib3  = ING + tt.idstoff[0];
    const u16* ibo  = ING + tt.idstoff[3];
    const u16* ig1  = ING + tt.idstoff[4];  const u16* ibe1 = ING + tt.idstoff[5];
    const u16* ibf1 = ING + tt.idstoff[6];  const u16* ibf2 = ING + tt.idstoff[7];
    const u16* ig2  = ING + tt.idstoff[8];  const u16* ibe2 = ING + tt.idstoff[9];
    const u16* iWl  = ING + tt.idstoff[10]; const u16* ibl  = ING + tt.idstoff[11];
    const u16* ibp1 = ING + tt.idstoff[12]; const u16* iWp2 = ING + tt.idstoff[13];
    const u16* ibp2 = ING + tt.idstoff[14]; const u16* iwc  = ING + tt.idstoff[15];
    const u16* ibc  = ING + tt.idstoff[16];

    // 0) detect (plain partials)
    k_detect<<<64, 256, 0, stream>>>((const u16*)d_in[14], DETP);
    // 1) prep: transposes + small ingest + embedding, one launch
    k_prep<<<ts + 17 + 2048, 256, 0, stream>>>(tt, DETP);
    // 2) fused QKV projection; V columns written directly in VT layout
    k_gemm64<<<1536, 256, 0, stream>>>(X, W3T, ib3, QKVb, 768, 256, 0, 6, 32, VT);
    // 3) attention
    k_attn_mfma<<<1024, 256, 0, stream>>>(QKVb, VT, CTX);
    // 4) fused Wo GEMM + residual + LN1 -> Y1
    k_wo_ln<<<1024, 256, 0, stream>>>(CTX, WoT, ibo, X, ig1, ibe1, Y1);
    // 5) FFN: FFN1 128-tile 2-phase dbuf, FFN2 64x64 high-TLP
    k_gemm_bt<<<16 * 128, 256, 0, stream>>>(Y1, W1T, ibf1, Hb, 2048, 256, 1, 16);
    k_gemm64n<<<1024, 256, 0, stream>>>(Hb, W2T, ibf2, FFO, 256, 2048, 0, 4, 32, nullptr);
    // 6) LN2 + logits / KL / flags (fused; writes Y2, KL partials)
    k_logits<<<1024, 256, 0, stream>>>(FFO, Y1, ig2, ibe2, iWl, ibl, Y2, KLP, FLAGS);
    // 7) per-batch exclusive scan
    k_scan<<<16, 1024, 0, stream>>>(FLAGS, SEG);
    // 8) segment means (4 segments per block)
    k_segmean<<<4096, 256, 0, stream>>>(Y2, SEG, MEANS, CNT);
    // 9) fused predicate head (GEMM + Wp2 dot + sigmoid + partials)
    k_predhead<<<256, 256, 0, stream>>>(MEANS, Wp1T, ibp1, iWp2, ibp2, iwc, ibc, CNT, PREDP);
    // 10) finalize + store
    k_final<<<1, 64, 0, stream>>>(PREDP, KLP, DETP, d_out);
}